// Round 11
// baseline (432.380 us; speedup 1.0000x reference)
//
#include <hip/hip_runtime.h>
#include <hip/hip_bf16.h>
#include <math.h>

#define BATCH 8
#define SEQ   2048
#define DIM   512
#define NH    8
#define DHEAD 64
#define FFD   2048
#define TOPQ  39            // ceil(5*ln(2048)) with factor=5, min_k=5 (fixed harness inputs)
#define MROWS (BATCH*SEQ)   // 16384
#define KC    64            // keys per attention partial chunk (one wave)
#define NKC   (SEQ/KC)      // 32
#define PSTR  66            // partial stride: 64 ctx + m + l
#define QPAD  48            // TOPQ padded to 3 MFMA row-tiles

typedef __hip_bfloat16 bf16;
typedef __attribute__((ext_vector_type(8))) short short8;
typedef __attribute__((ext_vector_type(4))) short sh4;
typedef __attribute__((ext_vector_type(4))) float floatx4;

__device__ __forceinline__ float bf2f(short u){
    return __uint_as_float(((unsigned int)(unsigned short)u) << 16);
}
// pack 2 floats -> 2 bf16 (RNE) in one u32 via intrinsic casts (fast path).
__device__ __forceinline__ unsigned int pk_bf16(float a, float b){
    union { bf16 h; unsigned short u; } ca, cb;
    ca.h = __float2bfloat16(a); cb.h = __float2bfloat16(b);
    return (unsigned int)ca.u | ((unsigned int)cb.u << 16);
}
// fast gelu, sigmoid form: v*sigmoid(2u); rcp ~1ulp << bf16 rounding.
__device__ __forceinline__ float gelu_f(float v){
    float u = v*(0.7978845608028654f + 0.0356774081363f*v*v);
    float e = __expf(-2.f*u);
    return v*__builtin_amdgcn_rcpf(1.f + e);
}

// async global->LDS, 16 B per lane; LDS dest = wave-uniform base + lane*16
__device__ __forceinline__ void load_lds16(const void* g, void* l){
    auto gp = reinterpret_cast<const uint32_t __attribute__((address_space(1)))*>(
        reinterpret_cast<uintptr_t>(g));
    auto lp = reinterpret_cast<uint32_t __attribute__((address_space(3)))*>(
        reinterpret_cast<uintptr_t>(l));
    __builtin_amdgcn_global_load_lds(gp, lp, 16, 0, 0);
}

// 16x16x16 bf16 MFMA (K=16): A/B = 4 bf16/lane, C/D std 16x16 map
__device__ __forceinline__ floatx4 mfma16(sh4 a, sh4 b, floatx4 c){
#if __has_builtin(__builtin_amdgcn_mfma_f32_16x16x16bf16_1k)
    return __builtin_amdgcn_mfma_f32_16x16x16bf16_1k(a, b, c, 0, 0, 0);
#elif __has_builtin(__builtin_amdgcn_mfma_f32_16x16x16_bf16)
    return __builtin_amdgcn_mfma_f32_16x16x16_bf16(a, b, c, 0, 0, 0);
#else
    asm volatile("v_mfma_f32_16x16x16_bf16 %0, %1, %2, %0\n\ts_nop 7\n\ts_nop 7"
                 : "+v"(c) : "v"(a), "v"(b));
    return c;
#endif
}

// transpose-read: 4 bf16 at elem strides {0,16,32,48} from per-lane LDS addr
__device__ __forceinline__ sh4 tr16_read(const short* p){
#if __has_builtin(__builtin_amdgcn_ds_read_tr16_b64_v4i16)
    auto lp = (__attribute__((address_space(3))) sh4*)(uintptr_t)p;
    return __builtin_amdgcn_ds_read_tr16_b64_v4i16(lp);
#elif __has_builtin(__builtin_amdgcn_ds_read_tr16_b64)
    auto lp = (__attribute__((address_space(3))) sh4*)(uintptr_t)p;
    return __builtin_amdgcn_ds_read_tr16_b64(lp);
#else
    sh4 r; r[0] = p[0]; r[1] = p[16]; r[2] = p[32]; r[3] = p[48]; return r;
#endif
}

__device__ __forceinline__ void store_out(bf16* p, float v){ *p = __float2bfloat16(v); }
__device__ __forceinline__ void store_out(float* p, float v){ *p = v; }

// ---------------------------------------------------------------------------
// 128x128-tile GEMM (proven): C = A(MxK)·B(NxK)^T + bias. Depth-2 pipeline,
// counted vmcnt. EPI: 1 = gelu->bf16 (FFN1), 2 = +x2 -> fp32 (FFN2).
// (KV projection now lives in kv_xbar_kernel; this template instantiated for
//  EPI 1/2 only, code unchanged to protect FFN codegen.)
// ---------------------------------------------------------------------------
template<int EPI, typename OUT_T>
__global__ __launch_bounds__(256, 3) void gemm128_kernel(const bf16* __restrict__ A,
                                                         const bf16* __restrict__ Bm,
                                                         const float* __restrict__ bias,
                                                         OUT_T* __restrict__ C,
                                                         const float* __restrict__ x2,
                                                         bf16* __restrict__ Vhm,
                                                         int K, int ldc, int lgGX)
{
    __shared__ __align__(16) char smem[49152];   // 3 x (As 8KB | Bs 8KB)
    short* CsBase = (short*)smem;

    const int bid = blockIdx.x;
    const int per = gridDim.x >> 3;
    const int lid = (bid & 7)*per + (bid >> 3);
    const int bx  = lid & ((1 << lgGX) - 1);
    const int by  = lid >> lgGX;

    const int t    = threadIdx.x;
    const int lane = t & 63;
    const int w    = t >> 6;
    const int lf   = lane & 15;
    const int ko   = lane >> 4;
    const int slot = ko ^ ((lf >> 1) & 3);
    const int mrow = (w >> 1)*64, ncol = (w & 1)*64;

    floatx4 acc[4][4];
    floatx4 z = {0.f,0.f,0.f,0.f};
    #pragma unroll
    for (int i = 0; i < 4; ++i)
        #pragma unroll
        for (int j = 0; j < 4; ++j) acc[i][j] = z;

    const int srow = w*16 + (lane >> 2);
    const int sq   = lane & 3;
    const int r0 = srow,      kq0 = sq ^ ((r0 >> 1) & 3);
    const int r1 = 64 + srow, kq1 = sq ^ ((r1 >> 1) & 3);
    const short* ga0 = (const short*)A  + ((size_t)by*128 + r0)*K + kq0*8;
    const short* ga1 = (const short*)A  + ((size_t)by*128 + r1)*K + kq1*8;
    const short* gb0 = (const short*)Bm + ((size_t)bx*128 + r0)*K + kq0*8;
    const short* gb1 = (const short*)Bm + ((size_t)bx*128 + r1)*K + kq1*8;
    char* la0 = smem + w*1024;
    char* la1 = smem + 4096 + w*1024;
    char* lb0 = smem + 8192 + w*1024;
    char* lb1 = smem + 12288 + w*1024;

    auto stage = [&](int off){
        load_lds16(ga0, la0 + off); load_lds16(ga1, la1 + off);
        load_lds16(gb0, lb0 + off); load_lds16(gb1, lb1 + off);
        ga0 += 32; ga1 += 32; gb0 += 32; gb1 += 32;
    };
    auto compute = [&](int off){
        const short* As = (const short*)(smem + off);
        const short* Bs = (const short*)(smem + off + 8192);
        short8 af[4], bfr[4];
        #pragma unroll
        for (int i = 0; i < 4; ++i){
            af[i]  = *(const short8*)(As + (mrow + i*16 + lf)*32 + slot*8);
            bfr[i] = *(const short8*)(Bs + (ncol + i*16 + lf)*32 + slot*8);
        }
        #pragma unroll
        for (int i = 0; i < 4; ++i)
            #pragma unroll
            for (int j = 0; j < 4; ++j)
                acc[i][j] = __builtin_amdgcn_mfma_f32_16x16x32_bf16(af[i], bfr[j], acc[i][j], 0, 0, 0);
    };

    const int T = K >> 5;
    stage(0);
    stage(16384);
    int oc = 0, on = 16384, on2 = 32768;
    for (int kt = 0; kt < T - 2; ++kt){
        asm volatile("s_waitcnt vmcnt(4)" ::: "memory");
        __builtin_amdgcn_s_barrier();
        asm volatile("" ::: "memory");
        stage(on2);
        compute(oc);
        int tmp = oc; oc = on; on = on2; on2 = tmp;
    }
    asm volatile("s_waitcnt vmcnt(4)" ::: "memory");
    __builtin_amdgcn_s_barrier();
    asm volatile("" ::: "memory");
    compute(oc);
    { int tmp = oc; oc = on; on = on2; on2 = tmp; }
    asm volatile("s_waitcnt vmcnt(0)" ::: "memory");
    __builtin_amdgcn_s_barrier();
    asm volatile("" ::: "memory");
    compute(oc);
    __syncthreads();

    if constexpr (EPI == 2){
        const int lr = ko*4;
        #pragma unroll
        for (int j = 0; j < 4; ++j){
            int gcol = bx*128 + ncol + j*16 + lf;
            float bv = bias[gcol];
            #pragma unroll
            for (int i = 0; i < 4; ++i){
                #pragma unroll
                for (int r = 0; r < 4; ++r){
                    size_t grow = (size_t)by*128 + mrow + i*16 + lr + r;
                    float v = acc[i][j][r] + bv + x2[grow*ldc + gcol];
                    store_out(&C[grow*ldc + gcol], v);
                }
            }
        }
    } else {
        short* cs = CsBase + w*(64*72);
        const int odd = lf & 1;
        const int rsel = odd*2;
        #pragma unroll
        for (int j = 0; j < 4; ++j){
            float bv = bias[bx*128 + ncol + j*16 + lf];
            #pragma unroll
            for (int i = 0; i < 4; ++i){
                float vv0 = acc[i][j][0] + bv;
                float vv1 = acc[i][j][1] + bv;
                float vv2 = acc[i][j][2] + bv;
                float vv3 = acc[i][j][3] + bv;
                if constexpr (EPI == 1){
                    vv0 = gelu_f(vv0); vv1 = gelu_f(vv1);
                    vv2 = gelu_f(vv2); vv3 = gelu_f(vv3);
                }
                unsigned long long self = (unsigned long long)pk_bf16(vv0, vv1)
                                        | ((unsigned long long)pk_bf16(vv2, vv3) << 32);
                unsigned long long nbr = __shfl_xor(self, 1);
                unsigned long long lo = odd ? nbr : self;
                unsigned long long hi = odd ? self : nbr;
                int colb = 16*j + (lf & ~1);
                unsigned int w0 = (unsigned int)((lo >> (16*rsel)) & 0xffffu)
                                | ((unsigned int)((hi >> (16*rsel)) & 0xffffu) << 16);
                unsigned int w1 = (unsigned int)((lo >> (16*(rsel+1))) & 0xffffu)
                                | ((unsigned int)((hi >> (16*(rsel+1))) & 0xffffu) << 16);
                *(unsigned int*)(cs + (16*i + 4*ko + rsel    )*72 + colb) = w0;
                *(unsigned int*)(cs + (16*i + 4*ko + rsel + 1)*72 + colb) = w1;
            }
        }
        const int subrow = lane >> 3, cq = lane & 7;
        #pragma unroll
        for (int rr = 0; rr < 8; ++rr){
            int rl = rr*8 + subrow;
            short8 vv = *(const short8*)(cs + rl*72 + cq*8);
            size_t grow = (size_t)by*128 + mrow + rl;
            int gcol = bx*128 + ncol + cq*8;
            *(short8*)((short*)C + grow*ldc + gcol) = vv;
        }
    }
}

// ---------------------------------------------------------------------------
// Round-18 merge A: LN1 + prep in one launch (independent work, block ranges:
// [0,16384) = LN1 rows; [16384,19008) = selmap init + 3 weight converts).
// LN1: one-pass paired fp64 reduction (proven round-15).
// ---------------------------------------------------------------------------
__global__ __launch_bounds__(256) void ln1_prep_kernel(const float* __restrict__ x,
                                                       const float* __restrict__ g,
                                                       const float* __restrict__ bt,
                                                       float* __restrict__ xn,
                                                       bf16* __restrict__ xnb,
                                                       const float* __restrict__ in_w,
                                                       const float* __restrict__ w1,
                                                       const float* __restrict__ w2,
                                                       bf16* __restrict__ kvw_b,
                                                       bf16* __restrict__ w1_b,
                                                       bf16* __restrict__ w2_b,
                                                       int* __restrict__ selmap)
{
    __shared__ double sbuf[8];
    int bid = blockIdx.x, t = threadIdx.x;
    if (bid >= MROWS){
        int pb = bid - MROWS;
        if (pb < 64){
            selmap[pb*256 + t] = -1;
            return;
        }
        const float* src; bf16* dst; int i;
        if (pb < 576){       src = in_w + (size_t)DIM*DIM; dst = kvw_b; i = ((pb - 64)*256 + t)*4; }
        else if (pb < 1600){ src = w1;  dst = w1_b; i = ((pb - 576)*256 + t)*4; }
        else {               src = w2;  dst = w2_b; i = ((pb - 1600)*256 + t)*4; }
        float4 v = *(const float4*)(src + i);
        dst[i+0] = __float2bfloat16(v.x);
        dst[i+1] = __float2bfloat16(v.y);
        dst[i+2] = __float2bfloat16(v.z);
        dst[i+3] = __float2bfloat16(v.w);
        return;
    }
    int row = bid;
    size_t base = (size_t)row*DIM;
    double x0 = (double)x[base + t];
    double x1 = (double)x[base + t + 256];
    double a = x0 + x1, q = x0*x0 + x1*x1;
    #pragma unroll
    for (int off = 32; off > 0; off >>= 1){
        a += __shfl_down(a, off);
        q += __shfl_down(q, off);
    }
    if ((t & 63) == 0){ sbuf[t >> 6] = a; sbuf[4 + (t >> 6)] = q; }
    __syncthreads();
    double sx  = sbuf[0] + sbuf[1] + sbuf[2] + sbuf[3];
    double sxx = sbuf[4] + sbuf[5] + sbuf[6] + sbuf[7];
    double m   = sx*(1.0/DIM);
    double var = sxx*(1.0/DIM) - m*m;
    double r = 1.0/sqrt(var + 1e-5);
    double y0 = (x0 - m)*r*(double)g[t]     + (double)bt[t];
    double y1 = (x1 - m)*r*(double)g[t+256] + (double)bt[t+256];
    xn[base+t] = (float)y0;       xn[base+t+256] = (float)y1;
    xnb[base+t] = __float2bfloat16((float)y0);
    xnb[base+t+256] = __float2bfloat16((float)y1);
}

// ---------------------------------------------------------------------------
// Round-18 merge B: KV projection GEMM (blocks [0,1024), EPI-3 body with
// per=128 hardcoded) + xbar column-sum partials (blocks [1024,1280), 256-thr
// version: 2 cols/thread). Both depend only on ln1 -> one launch.
// ---------------------------------------------------------------------------
__global__ __launch_bounds__(256, 3) void kv_xbar_kernel(const bf16* __restrict__ A,
                                                         const bf16* __restrict__ Bm,
                                                         const float* __restrict__ bias,
                                                         bf16* __restrict__ Khm,
                                                         bf16* __restrict__ Vhm,
                                                         const float* __restrict__ xn,
                                                         double* __restrict__ xbpart)
{
    __shared__ __align__(16) char smem[49152];
    const int t = threadIdx.x;
    if (blockIdx.x >= 1024){
        int cid = blockIdx.x - 1024;          // 0..255
        int b = cid >> 5, c = cid & 31;
        const float* p = xn + ((size_t)b*SEQ + c*64)*DIM + t;
        double s0 = 0.0, s1 = 0.0;
        #pragma unroll 8
        for (int i = 0; i < 64; ++i){
            s0 += (double)p[(size_t)i*DIM];
            s1 += (double)p[(size_t)i*DIM + 256];
        }
        xbpart[((size_t)(b*32 + c))*DIM + t]       = s0;
        xbpart[((size_t)(b*32 + c))*DIM + t + 256] = s1;
        return;
    }
    short* CsBase = (short*)smem;
    const int K = DIM;                        // 512, T = 16
    const int bid = blockIdx.x;
    const int per = 128;                      // 1024 gemm blocks / 8 XCDs
    const int lid = (bid & 7)*per + (bid >> 3);
    const int bx  = lid & 7;                  // lgGX = 3
    const int by  = lid >> 3;

    const int lane = t & 63;
    const int w    = t >> 6;
    const int lf   = lane & 15;
    const int ko   = lane >> 4;
    const int slot = ko ^ ((lf >> 1) & 3);
    const int mrow = (w >> 1)*64, ncol = (w & 1)*64;

    floatx4 acc[4][4];
    floatx4 z = {0.f,0.f,0.f,0.f};
    #pragma unroll
    for (int i = 0; i < 4; ++i)
        #pragma unroll
        for (int j = 0; j < 4; ++j) acc[i][j] = z;

    const int srow = w*16 + (lane >> 2);
    const int sq   = lane & 3;
    const int r0 = srow,      kq0 = sq ^ ((r0 >> 1) & 3);
    const int r1 = 64 + srow, kq1 = sq ^ ((r1 >> 1) & 3);
    const short* ga0 = (const short*)A  + ((size_t)by*128 + r0)*K + kq0*8;
    const short* ga1 = (const short*)A  + ((size_t)by*128 + r1)*K + kq1*8;
    const short* gb0 = (const short*)Bm + ((size_t)bx*128 + r0)*K + kq0*8;
    const short* gb1 = (const short*)Bm + ((size_t)bx*128 + r1)*K + kq1*8;
    char* la0 = smem + w*1024;
    char* la1 = smem + 4096 + w*1024;
    char* lb0 = smem + 8192 + w*1024;
    char* lb1 = smem + 12288 + w*1024;

    auto stage = [&](int off){
        load_lds16(ga0, la0 + off); load_lds16(ga1, la1 + off);
        load_lds16(gb0, lb0 + off); load_lds16(gb1, lb1 + off);
        ga0 += 32; ga1 += 32; gb0 += 32; gb1 += 32;
    };
    auto compute = [&](int off){
        const short* As = (const short*)(smem + off);
        const short* Bs = (const short*)(smem + off + 8192);
        short8 af[4], bfr[4];
        #pragma unroll
        for (int i = 0; i < 4; ++i){
            af[i]  = *(const short8*)(As + (mrow + i*16 + lf)*32 + slot*8);
            bfr[i] = *(const short8*)(Bs + (ncol + i*16 + lf)*32 + slot*8);
        }
        #pragma unroll
        for (int i = 0; i < 4; ++i)
            #pragma unroll
            for (int j = 0; j < 4; ++j)
                acc[i][j] = __builtin_amdgcn_mfma_f32_16x16x32_bf16(af[i], bfr[j], acc[i][j], 0, 0, 0);
    };

    const int T = K >> 5;
    stage(0);
    stage(16384);
    int oc = 0, on = 16384, on2 = 32768;
    for (int kt = 0; kt < T - 2; ++kt){
        asm volatile("s_waitcnt vmcnt(4)" ::: "memory");
        __builtin_amdgcn_s_barrier();
        asm volatile("" ::: "memory");
        stage(on2);
        compute(oc);
        int tmp = oc; oc = on; on = on2; on2 = tmp;
    }
    asm volatile("s_waitcnt vmcnt(4)" ::: "memory");
    __builtin_amdgcn_s_barrier();
    asm volatile("" ::: "memory");
    compute(oc);
    { int tmp = oc; oc = on; on = on2; on2 = tmp; }
    asm volatile("s_waitcnt vmcnt(0)" ::: "memory");
    __builtin_amdgcn_s_barrier();
    asm volatile("" ::: "memory");
    compute(oc);
    __syncthreads();

    // epilogue: bf16 pack -> LDS stage -> coalesced head-major K/V scatter
    short* cs = CsBase + w*(64*72);
    const int odd = lf & 1;
    const int rsel = odd*2;
    #pragma unroll
    for (int j = 0; j < 4; ++j){
        float bv = bias[bx*128 + ncol + j*16 + lf];
        #pragma unroll
        for (int i = 0; i < 4; ++i){
            float vv0 = acc[i][j][0] + bv;
            float vv1 = acc[i][j][1] + bv;
            float vv2 = acc[i][j][2] + bv;
            float vv3 = acc[i][j][3] + bv;
            unsigned long long self = (unsigned long long)pk_bf16(vv0, vv1)
                                    | ((unsigned long long)pk_bf16(vv2, vv3) << 32);
            unsigned long long nbr = __shfl_xor(self, 1);
            unsigned long long lo = odd ? nbr : self;
            unsigned long long hi = odd ? self : nbr;
            int colb = 16*j + (lf & ~1);
            unsigned int w0 = (unsigned int)((lo >> (16*rsel)) & 0xffffu)
                            | ((unsigned int)((hi >> (16*rsel)) & 0xffffu) << 16);
            unsigned int w1 = (unsigned int)((lo >> (16*(rsel+1))) & 0xffffu)
                            | ((unsigned int)((hi >> (16*(rsel+1))) & 0xffffu) << 16);
            *(unsigned int*)(cs + (16*i + 4*ko + rsel    )*72 + colb) = w0;
            *(unsigned int*)(cs + (16*i + 4*ko + rsel + 1)*72 + colb) = w1;
        }
    }
    const int subrow = lane >> 3, cq = lane & 7;
    #pragma unroll
    for (int rr = 0; rr < 8; ++rr){
        int rl = rr*8 + subrow;
        short8 vv = *(const short8*)(cs + rl*72 + cq*8);
        int grow = by*128 + mrow + rl;        // b*SEQ + s
        int b = grow >> 11, s = grow & 2047;
        int gc = bx*128 + ncol + cq*8;
        int h = (gc >> 6) & 7, d = gc & 63;
        bf16* dst = (gc < 512) ? Khm : Vhm;
        *(short8*)((short*)dst + (((size_t)(b*NH + h))*SEQ + s)*DHEAD + d) = vv;
    }
}

__global__ __launch_bounds__(512) void xbar_fin_kernel(const double* __restrict__ part,
                                                       double* __restrict__ xbar_d,
                                                       float* __restrict__ xbar_f){
    int b = blockIdx.x, d = threadIdx.x;
    double s = 0.0;
    for (int c = 0; c < 32; ++c) s += part[((size_t)(b*32 + c))*DIM + d];
    s *= (1.0/SEQ);
    xbar_d[(size_t)b*DIM + d] = s;
    xbar_f[(size_t)b*DIM + d] = (float)s;
}

// sparsity*sqrt(D) = Σxn² - dot(xn_row, xbar); fp64 over the SAME fp32 xn
// values ref uses -> ranking margin >> ref's own fp32 noise.
__global__ __launch_bounds__(256) void sparsity_kernel(const float* __restrict__ xn,
                                                       const double* __restrict__ xbar,
                                                       double* __restrict__ sp)
{
    int row  = blockIdx.x*4 + (threadIdx.x >> 6);
    int lane = threadIdx.x & 63;
    int b    = row >> 11;
    const float* xr = xn + (size_t)row*DIM;
    const double* xb = xbar + (size_t)b*DIM;
    double s = 0.0, d2 = 0.0;
    for (int e = lane; e < DIM; e += 64){
        double xv = (double)xr[e];
        s  += xv*xb[e];
        d2 += xv*xv;
    }
    #pragma unroll
    for (int off = 32; off > 0; off >>= 1){
        s  += __shfl_down(s, off);
        d2 += __shfl_down(d2, off);
    }
    if (lane == 0) sp[row] = d2 - s;
}

// ---------------------------------------------------------------------------
// register-resident top-39 (proven): packed monotone u64 order keys.
// ---------------------------------------------------------------------------
__global__ __launch_bounds__(256) void topk_kernel(const double* __restrict__ sp,
                                                   int* __restrict__ topidx,
                                                   int* __restrict__ selmap,
                                                   float* __restrict__ dout)
{
    __shared__ unsigned long long wmax[4];
    int b = blockIdx.x, t = threadIdx.x;
    int lane = t & 63, w = t >> 6;

    unsigned long long pk[8];
    #pragma unroll
    for (int i = 0; i < 8; ++i){
        int idx = i*256 + t;                          // coalesced
        unsigned long long bits =
            (unsigned long long)__double_as_longlong(sp[(size_t)b*SEQ + idx]);
        unsigned long long m = (bits & 0x8000000000000000ull)
                             ? ~bits : (bits | 0x8000000000000000ull);
        pk[i] = (m & ~2047ull) | (unsigned long long)(2047 - idx);
    }
    unsigned long long lm = pk[0];
    #pragma unroll
    for (int i = 1; i < 8; ++i) lm = (pk[i] > lm) ? pk[i] : lm;

    for (int it = 0; it < TOPQ; ++it){
        unsigned long long m = lm;
        #pragma unroll
        for (int off = 32; off > 0; off >>= 1){
            unsigned long long o = __shfl_xor(m, off);
            m = (o > m) ? o : m;
        }
        if (lane == 0) wmax[w] = m;
        __syncthreads();
        unsigned long long g01 = (wmax[0] > wmax[1]) ? wmax[0] : wmax[1];
        unsigned long long g23 = (wmax[2] > wmax[3]) ? wmax[2] : wmax[3];
        unsigned long long g = (g01 > g23) ? g01 : g23;
        int idx = 2047 - (int)(g & 2047ull);
        if (t == 0){
            topidx[b*64 + it] = idx;
            selmap[(size_t)b*SEQ + idx] = it;
        }
        if ((idx & 255) == t){                        // owner removes + recompute
            int slot = idx >> 8;
            #pragma unroll
            for (int i = 0; i < 8; ++i) if (i == slot) pk[i] = 0;
            lm = pk[0];
            #pragma unroll
            for (int i = 1; i < 8; ++i) lm = (pk[i] > lm) ? pk[i] : lm;
        }
        __syncthreads();                              // wmax reuse safety
    }
    if (b == 0 && t == 0) dout[(size_t)MROWS*DIM] = (float)TOPQ/(float)SEQ;
}

// ---------------------------------------------------------------------------
// qproj v2: 32x-parallel (proven). grid (32, QPAD, BATCH).
// ---------------------------------------------------------------------------
__global__ __launch_bounds__(256) void qproj_kernel(const float* __restrict__ xn,
                                                    const float* __restrict__ in_w,
                                                    const float* __restrict__ in_b,
                                                    const int* __restrict__ topidx,
                                                    bf16* __restrict__ Qhm)
{
    __shared__ float qr[DIM];
    int dblk = blockIdx.x, j = blockIdx.y, b = blockIdx.z;
    int t = threadIdx.x;
    int o = t >> 4, ks = t & 15;
    int d0 = dblk*16 + o;
    int h = d0 >> 6, d = d0 & 63;
    if (j >= TOPQ){
        if (ks == 0)
            Qhm[((size_t)(b*NH + h)*QPAD + j)*DHEAD + d] = __float2bfloat16(0.f);
        return;
    }
    int srow = topidx[b*64 + j];
    const float* xr = xn + ((size_t)(b*SEQ + srow))*DIM;
    qr[t] = xr[t]; qr[t + 256] = xr[t + 256];
    __syncthreads();
    const float* wr = in_w + (size_t)d0*DIM;
    float s = 0.f;
    #pragma unroll
    for (int i = 0; i < 8; ++i){
        int e = i*64 + ks*4;
        float4 wv = *(const float4*)(wr + e);
        float4 cv = *(const float4*)(qr + e);
        s += cv.x*wv.x + cv.y*wv.y + cv.z*wv.z + cv.w*wv.w;
    }
    #pragma unroll
    for (int off = 8; off > 0; off >>= 1) s += __shfl_down(s, off, 16);
    if (ks == 0)
        Qhm[((size_t)(b*NH + h)*QPAD + j)*DHEAD + d] = __float2bfloat16(s + in_b[d0]);
}

// ---------------------------------------------------------------------------
// MFMA split-K attention partial (KC=64, 2 blocks/CU).
// ---------------------------------------------------------------------------
__global__ __launch_bounds__(256, 1) void attn_mfma_kernel(const bf16* __restrict__ Qhm,
                                                           const bf16* __restrict__ Khm,
                                                           const bf16* __restrict__ Vhm,
                                                           float* __restrict__ part)
{
    __shared__ __align__(16) short vsm[4*4096];   // 32 KB: 4 waves x (64k x 64d)
    const int bh   = blockIdx.z*NH + blockIdx.y;
    const int w    = threadIdx.x >> 6;
    const int lane = threadIdx.x & 63;
    const int ch   = blockIdx.x*4 + w;           // chunk 0..31
    const int kb   = ch*KC;                      // first key of chunk
    const int lf   = lane & 15;
    const int g    = lane >> 4;

    short* vbase = vsm + w*4096;
    const short* vg = (const short*)Vhm + ((size_t)bh*SEQ + kb)*DHEAD;
    {
        const int kh = lane >> 1, dh = (lane & 1)*8;
        #pragma unroll
        for (int L = 0; L < 8; ++L){
            int k = (L & 1)*32 + kh;
            int d = (L >> 1)*16 + dh;
            load_lds16(vg + (size_t)k*DHEAD + d, vbase + L*512);
        }
    }

    short8 qf[3][2];
    const short* qp = (const short*)Qhm + (size_t)bh*QPAD*DHEAD;
    #pragma unroll
    for (int nt = 0; nt < 3; ++nt)
        #pragma unroll
        for (int s = 0; s < 2; ++s)
            qf[nt][s] = *(const short8*)(qp + (nt*16 + lf)*DHEAD + s*32 + g*8);

    floatx4 sa[4][3];
    floatx4 z = {0.f,0.f,0.f,0.f};
    #pragma unroll
    for (int mt = 0; mt < 4; ++mt)
        #pragma unroll
        for (int nt = 0; nt < 3; ++nt) sa[mt][nt] = z;

    const short* kp = (const short*)Khm + ((size_t)bh*SEQ + kb)*DHEAD;
    #pragma unroll
    for (int mt = 0; mt < 4; ++mt){
        const short* kr = kp + (size_t)(mt*16 + lf)*DHEAD + g*8;
        short8 kf0 = *(const short8*)(kr);
        short8 kf1 = *(const short8*)(kr + 32);
        #pragma unroll
        for (int nt = 0; nt < 3; ++nt){
            sa[mt][nt] = __builtin_amdgcn_mfma_f32_16x16x32_bf16(kf0, qf[nt][0], sa[mt][nt], 0, 0, 0);
            sa[mt][nt] = __builtin_amdgcn_mfma_f32_16x16x32_bf16(kf1, qf[nt][1], sa[mt][nt], 0, 0, 0);
        }
    }

    float mx[3], ls[3];
    #pragma unroll
    for (int nt = 0; nt < 3; ++nt){
        float m = sa[0][nt][0];
        #pragma unroll
        for (int mt = 0; mt < 4; ++mt)
            #pragma unroll
            for (int r = 0; r < 4; ++r) m = fmaxf(m, sa[mt][nt][r]);
        m = fmaxf(m, __shfl_xor(m, 16));
        m = fmaxf(m, __shfl_xor(m, 32));
        float l = 0.f;
        #pragma unroll
        for (int mt = 0; mt < 4; ++mt){
            #pragma unroll
            for (int r = 0; r < 4; ++r){
                float p = __expf((sa[mt][nt][r] - m)*0.125f);   // 1/sqrt(64)
                sa[mt][nt][r] = p;
                l += p;
            }
        }
        l += __shfl_xor(l, 16);
        l += __shfl_xor(l, 32);
        mx[nt] = m; ls[nt] = l;
    }

    asm volatile("s_waitcnt vmcnt(0)" ::: "memory");   // V staging landed
    floatx4 oacc[3][4];
    #pragma unroll
    for (int mi = 0; mi < 3; ++mi)
        #pragma unroll
        for (int dt = 0; dt < 4; ++dt) oacc[mi][dt] = z;

    #pragma unroll
    for (int t = 0; t < 4; ++t){
        sh4 pa[3];
        #pragma unroll
        for (int mi = 0; mi < 3; ++mi){
            union { sh4 v; unsigned u[2]; } pk;
            pk.u[0] = pk_bf16(sa[t][mi][0], sa[t][mi][1]);
            pk.u[1] = pk_bf16(sa[t][mi][2], sa[t][mi][3]);
            pa[mi] = pk.v;
        }
        #pragma unroll
        for (int dt = 0; dt < 4; ++dt){
            sh4 vf = tr16_read(vbase + dt*1024 + (t*16 + 4*g)*16 + lf);
            #pragma unroll
            for (int mi = 0; mi < 3; ++mi)
                oacc[mi][dt] = mfma16(pa[mi], vf, oacc[mi][dt]);
        }
    }

    float* pbase = part + ((size_t)bh*TOPQ*NKC + ch)*PSTR;
    #pragma unroll
    for (int mi = 0; mi < 3; ++mi){
        #pragma unroll
        for (int r = 0; r < 4; ++r){
            int q = mi*16 + 4*g + r;
            if (q < TOPQ){
                float* pp = pbase + (size_t)q*NKC*PSTR;
                #pragma unroll
                for (int dt = 0; dt < 4; ++dt)
                    pp[dt*16 + lf] = oacc[mi][dt][r];
            }
        }
    }
    #pragma unroll
    for (int nt = 0; nt < 3; ++nt){
        int q = nt*16 + lf;
        if (g == 3 && q < TOPQ){
            float* pp = pbase + (size_t)q*NKC*PSTR;
            pp[64] = mx[nt]*0.125f;
            pp[65] = ls[nt];
        }
    }
}

// ---------------------------------------------------------------------------
// Round-18 merge C: attn partial-merge + out-projection in ONE kernel.
// grid (32, TOPQ, BATCH); each block redundantly merges the 8 heads' 32
// partials into an LDS ctx row (apart is 21 MB -> fits aggregate L2; 32x
// redundancy = ~168 MB of L2 reads, cheap), then runs the PROVEN 16-output
// x 16-lane-split projection (round-16's outproj_v2). Kills the separate
// attn_reduce launch + the ctxb round-trip. (Round-8's merged version was
// slow due to its serial projection phase, not the merge.)
// ---------------------------------------------------------------------------
__global__ __launch_bounds__(256) void attn_out2_kernel(const float* __restrict__ part,
                                                        const float* __restrict__ ow,
                                                        const float* __restrict__ ob,
                                                        float* __restrict__ sout)
{
    __shared__ float cr[DIM];
    int dblk = blockIdx.x, q = blockIdx.y, b = blockIdx.z;
    int t = threadIdx.x, w = t >> 6, lane = t & 63;
    #pragma unroll
    for (int hh = 0; hh < 2; ++hh){
        int h = w*2 + hh;
        const float* pb = part + (((size_t)(b*NH + h))*TOPQ + q)*NKC*PSTR;
        float M = -3.402823466e38f;
        #pragma unroll
        for (int i = 0; i < NKC; ++i) M = fmaxf(M, pb[i*PSTR + 64]);
        float L = 0.f, a = 0.f;
        #pragma unroll
        for (int i = 0; i < NKC; ++i){
            float sc = __expf(pb[i*PSTR + 64] - M);
            L += pb[i*PSTR + 65]*sc;
            a += pb[i*PSTR + lane]*sc;
        }
        cr[h*64 + lane] = a/L;
    }
    __syncthreads();
    int o = t >> 4, ks = t & 15;
    int d0 = dblk*16 + o;
    const float* wr = ow + (size_t)d0*DIM;
    float s = 0.f;
    #pragma unroll
    for (int i = 0; i < 8; ++i){
        int e = i*64 + ks*4;
        float4 wv = *(const float4*)(wr + e);
        float4 cv = *(const float4*)(cr + e);
        s += cv.x*wv.x + cv.y*wv.y + cv.z*wv.z + cv.w*wv.w;
    }
    #pragma unroll
    for (int off = 8; off > 0; off >>= 1) s += __shfl_down(s, off, 16);
    if (ks == 0) sout[((size_t)(b*TOPQ + q))*DIM + d0] = s + ob[d0];
}

// ---------------------------------------------------------------------------
// res+LN2: ONE-PASS paired fp32 reduction (Σv, Σv²); 1 barrier.
// ---------------------------------------------------------------------------
__global__ __launch_bounds__(256) void res_ln2_kernel(const float* __restrict__ x,
                                                      const float* __restrict__ xbar,
                                                      const float* __restrict__ sout,
                                                      const int* __restrict__ selmap,
                                                      const float* __restrict__ g2,
                                                      const float* __restrict__ bt2,
                                                      float* __restrict__ x2,
                                                      bf16* __restrict__ hb)
{
    __shared__ float sbuf[8];
    int row = blockIdx.x;
    int b = row >> 11;
    int t = threadIdx.x;
    int slot = selmap[row];
    const float* ar = (slot >= 0) ? (sout + ((size_t)(b*TOPQ + slot))*DIM)
                                  : (xbar + (size_t)b*DIM);
    size_t base = (size_t)row*DIM;
    float v0 = x[base + t]       + ar[t];
    float v1 = x[base + t + 256] + ar[t + 256];
    x2[base + t] = v0; x2[base + t + 256] = v1;
    float a = v0 + v1, q = v0*v0 + v1*v1;
    #pragma unroll
    for (int off = 32; off > 0; off >>= 1){
        a += __shfl_down(a, off);
        q += __shfl_down(q, off);
    }
    if ((t & 63) == 0){ sbuf[t >> 6] = a; sbuf[4 + (t >> 6)] = q; }
    __syncthreads();
    float sv  = sbuf[0] + sbuf[1] + sbuf[2] + sbuf[3];
    float svv = sbuf[4] + sbuf[5] + sbuf[6] + sbuf[7];
    float m   = sv*(1.f/DIM);
    float var = svv*(1.f/DIM) - m*m;
    float r = 1.f/sqrtf(var + 1e-5f);
    hb[base + t]       = __float2bfloat16((v0 - m)*r*g2[t]     + bt2[t]);
    hb[base + t + 256] = __float2bfloat16((v1 - m)*r*g2[t+256] + bt2[t+256]);
}

// ---------------------------------------------------------------------------
extern "C" void kernel_launch(void* const* d_in, const int* in_sizes, int n_in,
                              void* d_out, int out_size, void* d_ws, size_t ws_size,
                              hipStream_t stream)
{
    (void)in_sizes; (void)n_in; (void)out_size; (void)ws_size;
    const float* x     = (const float*)d_in[0];
    const float* ln1_g = (const float*)d_in[1];
    const float* ln1_b = (const float*)d_in[2];
    const float* in_w  = (const float*)d_in[3];
    const float* in_b  = (const float*)d_in[4];
    const float* out_w = (const float*)d_in[5];
    const float* out_b = (const float*)d_in[6];
    const float* ln2_g = (const float*)d_in[7];
    const float* ln2_b = (const float*)d_in[8];
    const float* w1    = (const float*)d_in[9];
    const float* b1    = (const float*)d_in[10];
    const float* w2    = (const float*)d_in[11];
    const float* b2    = (const float*)d_in[12];
    float* out = (float*)d_out;

    const size_t MB = 1024*1024;
    char* base = (char*)d_ws;
    float* xn_f  = (float*)base;                 // [0,32MiB); reused as x2_f later
    bf16*  xn_b  = (bf16*)(base + 32*MB);        // dead after kv-gemm -> h_b
    bf16*  Khm   = (bf16*)(base + 48*MB);
    bf16*  Vhm   = (bf16*)(base + 64*MB);
    bf16*  h_b   = (bf16*)(base + 32*MB);
    bf16*  h1_b  = (bf16*)(base + 48*MB);        // overwrites Khm/Vhm after attn
    float* x2_f  = xn_f;
    // apart (21 MiB) lives at [80,101) MiB: free during attention (h1_b rows
    // covering it are written only by FFN1, after attn_out2 consumed apart).
    float* apart = (float*)(base + 80*MB);
    char* p = base + 112*MB;
    bf16*  kvw_b  = (bf16*)p;  p += (size_t)1024*DIM*2;        // in_w rows [512,1536) bf16
    bf16*  w1_b   = (bf16*)p;  p += (size_t)FFD*DIM*2;
    bf16*  w2_b   = (bf16*)p;  p += (size_t)DIM*FFD*2;
    double* xbpart= (double*)p; p += (size_t)BATCH*32*DIM*8;
    double* xbar_d= (double*)p; p += (size_t)BATCH*DIM*8;
    float* xbar_f = (float*)p;  p += (size_t)BATCH*DIM*4;
    double* spars = (double*)p; p += (size_t)MROWS*8;
    int*   topidx = (int*)p;    p += (size_t)BATCH*64*4;
    int*   selmap = (int*)p;    p += (size_t)MROWS*4;
    bf16*  Qhm    = (bf16*)p;   p += (size_t)BATCH*NH*QPAD*DHEAD*2;   // 384 KiB
    float* sout   = (float*)p;  p += (size_t)BATCH*TOPQ*DIM*4;

    // 11 dispatches (was 14): prep+ln1, KV+xbar_part, reduce+outproj merged.
    ln1_prep_kernel<<<MROWS + 2624, 256, 0, stream>>>(
        x, ln1_g, ln1_b, xn_f, xn_b, in_w, w1, w2, kvw_b, w1_b, w2_b, selmap);
    kv_xbar_kernel<<<1280, 256, 0, stream>>>(
        xn_b, kvw_b, in_b + DIM, Khm, Vhm, xn_f, xbpart);
    xbar_fin_kernel<<<BATCH, 512, 0, stream>>>(xbpart, xbar_d, xbar_f);
    sparsity_kernel<<<MROWS/4, 256, 0, stream>>>(xn_f, xbar_d, spars);
    topk_kernel<<<BATCH, 256, 0, stream>>>(spars, topidx, selmap, out);
    qproj_kernel<<<dim3(32, QPAD, BATCH), 256, 0, stream>>>(xn_f, in_w, in_b, topidx, Qhm);
    attn_mfma_kernel<<<dim3(NKC/4, NH, BATCH), 256, 0, stream>>>(Qhm, Khm, Vhm, apart);
    attn_out2_kernel<<<dim3(32, TOPQ, BATCH), 256, 0, stream>>>(apart, out_w, out_b, sout);
    res_ln2_kernel<<<MROWS, 256, 0, stream>>>(x, xbar_f, sout, selmap, ln2_g, ln2_b, x2_f, h_b);
    // FFN1: grid 16x128 -> 2048 blocks, lgGX=4
    gemm128_kernel<1, bf16><<<2048, 256, 0, stream>>>(
        h_b, w1_b, b1, h1_b, nullptr, nullptr, DIM, FFD, 4);
    // FFN2: grid 4x128 -> 512 blocks, lgGX=2
    gemm128_kernel<2, float><<<512, 256, 0, stream>>>(
        h1_b, w2_b, b2, out, x2_f, nullptr, FFD, DIM, 2);
}

// Round 12
// 353.096 us; speedup vs baseline: 1.2245x; 1.2245x over previous
//
#include <hip/hip_runtime.h>
#include <hip/hip_bf16.h>
#include <math.h>

#define BATCH 8
#define SEQ   2048
#define DIM   512
#define NH    8
#define DHEAD 64
#define FFD   2048
#define TOPQ  39            // ceil(5*ln(2048)) with factor=5, min_k=5 (fixed harness inputs)
#define MROWS (BATCH*SEQ)   // 16384
#define KC    64            // keys per attention partial chunk (one wave)
#define NKC   (SEQ/KC)      // 32
#define PSTR  66            // partial stride: 64 ctx + m + l
#define QPAD  48            // TOPQ padded to 3 MFMA row-tiles

typedef __hip_bfloat16 bf16;
typedef __attribute__((ext_vector_type(8))) short short8;
typedef __attribute__((ext_vector_type(4))) short sh4;
typedef __attribute__((ext_vector_type(4))) float floatx4;

__device__ __forceinline__ float bf2f(short u){
    return __uint_as_float(((unsigned int)(unsigned short)u) << 16);
}
// pack 2 floats -> 2 bf16 (RNE) in one u32 via intrinsic casts (fast path).
__device__ __forceinline__ unsigned int pk_bf16(float a, float b){
    union { bf16 h; unsigned short u; } ca, cb;
    ca.h = __float2bfloat16(a); cb.h = __float2bfloat16(b);
    return (unsigned int)ca.u | ((unsigned int)cb.u << 16);
}
// fast gelu, sigmoid form: v*sigmoid(2u); rcp ~1ulp << bf16 rounding.
__device__ __forceinline__ float gelu_f(float v){
    float u = v*(0.7978845608028654f + 0.0356774081363f*v*v);
    float e = __expf(-2.f*u);
    return v*__builtin_amdgcn_rcpf(1.f + e);
}

// async global->LDS, 16 B per lane; LDS dest = wave-uniform base + lane*16
__device__ __forceinline__ void load_lds16(const void* g, void* l){
    auto gp = reinterpret_cast<const uint32_t __attribute__((address_space(1)))*>(
        reinterpret_cast<uintptr_t>(g));
    auto lp = reinterpret_cast<uint32_t __attribute__((address_space(3)))*>(
        reinterpret_cast<uintptr_t>(l));
    __builtin_amdgcn_global_load_lds(gp, lp, 16, 0, 0);
}

// 16x16x16 bf16 MFMA (K=16): A/B = 4 bf16/lane, C/D std 16x16 map
__device__ __forceinline__ floatx4 mfma16(sh4 a, sh4 b, floatx4 c){
#if __has_builtin(__builtin_amdgcn_mfma_f32_16x16x16bf16_1k)
    return __builtin_amdgcn_mfma_f32_16x16x16bf16_1k(a, b, c, 0, 0, 0);
#elif __has_builtin(__builtin_amdgcn_mfma_f32_16x16x16_bf16)
    return __builtin_amdgcn_mfma_f32_16x16x16_bf16(a, b, c, 0, 0, 0);
#else
    asm volatile("v_mfma_f32_16x16x16_bf16 %0, %1, %2, %0\n\ts_nop 7\n\ts_nop 7"
                 : "+v"(c) : "v"(a), "v"(b));
    return c;
#endif
}

// transpose-read: 4 bf16 at elem strides {0,16,32,48} from per-lane LDS addr
__device__ __forceinline__ sh4 tr16_read(const short* p){
#if __has_builtin(__builtin_amdgcn_ds_read_tr16_b64_v4i16)
    auto lp = (__attribute__((address_space(3))) sh4*)(uintptr_t)p;
    return __builtin_amdgcn_ds_read_tr16_b64_v4i16(lp);
#elif __has_builtin(__builtin_amdgcn_ds_read_tr16_b64)
    auto lp = (__attribute__((address_space(3))) sh4*)(uintptr_t)p;
    return __builtin_amdgcn_ds_read_tr16_b64(lp);
#else
    sh4 r; r[0] = p[0]; r[1] = p[16]; r[2] = p[32]; r[3] = p[48]; return r;
#endif
}

__device__ __forceinline__ void store_out(bf16* p, float v){ *p = __float2bfloat16(v); }
__device__ __forceinline__ void store_out(float* p, float v){ *p = v; }

// ---------------------------------------------------------------------------
// 128x128-tile GEMM (proven): C = A(MxK)·B(NxK)^T + bias. Depth-2 pipeline,
// counted vmcnt. EPI: 1 = gelu->bf16 (FFN1), 2 = +x2 -> fp32 (FFN2).
// ---------------------------------------------------------------------------
template<int EPI, typename OUT_T>
__global__ __launch_bounds__(256, 3) void gemm128_kernel(const bf16* __restrict__ A,
                                                         const bf16* __restrict__ Bm,
                                                         const float* __restrict__ bias,
                                                         OUT_T* __restrict__ C,
                                                         const float* __restrict__ x2,
                                                         bf16* __restrict__ Vhm,
                                                         int K, int ldc, int lgGX)
{
    __shared__ __align__(16) char smem[49152];   // 3 x (As 8KB | Bs 8KB)
    short* CsBase = (short*)smem;

    const int bid = blockIdx.x;
    const int per = gridDim.x >> 3;
    const int lid = (bid & 7)*per + (bid >> 3);
    const int bx  = lid & ((1 << lgGX) - 1);
    const int by  = lid >> lgGX;

    const int t    = threadIdx.x;
    const int lane = t & 63;
    const int w    = t >> 6;
    const int lf   = lane & 15;
    const int ko   = lane >> 4;
    const int slot = ko ^ ((lf >> 1) & 3);
    const int mrow = (w >> 1)*64, ncol = (w & 1)*64;

    floatx4 acc[4][4];
    floatx4 z = {0.f,0.f,0.f,0.f};
    #pragma unroll
    for (int i = 0; i < 4; ++i)
        #pragma unroll
        for (int j = 0; j < 4; ++j) acc[i][j] = z;

    const int srow = w*16 + (lane >> 2);
    const int sq   = lane & 3;
    const int r0 = srow,      kq0 = sq ^ ((r0 >> 1) & 3);
    const int r1 = 64 + srow, kq1 = sq ^ ((r1 >> 1) & 3);
    const short* ga0 = (const short*)A  + ((size_t)by*128 + r0)*K + kq0*8;
    const short* ga1 = (const short*)A  + ((size_t)by*128 + r1)*K + kq1*8;
    const short* gb0 = (const short*)Bm + ((size_t)bx*128 + r0)*K + kq0*8;
    const short* gb1 = (const short*)Bm + ((size_t)bx*128 + r1)*K + kq1*8;
    char* la0 = smem + w*1024;
    char* la1 = smem + 4096 + w*1024;
    char* lb0 = smem + 8192 + w*1024;
    char* lb1 = smem + 12288 + w*1024;

    auto stage = [&](int off){
        load_lds16(ga0, la0 + off); load_lds16(ga1, la1 + off);
        load_lds16(gb0, lb0 + off); load_lds16(gb1, lb1 + off);
        ga0 += 32; ga1 += 32; gb0 += 32; gb1 += 32;
    };
    auto compute = [&](int off){
        const short* As = (const short*)(smem + off);
        const short* Bs = (const short*)(smem + off + 8192);
        short8 af[4], bfr[4];
        #pragma unroll
        for (int i = 0; i < 4; ++i){
            af[i]  = *(const short8*)(As + (mrow + i*16 + lf)*32 + slot*8);
            bfr[i] = *(const short8*)(Bs + (ncol + i*16 + lf)*32 + slot*8);
        }
        #pragma unroll
        for (int i = 0; i < 4; ++i)
            #pragma unroll
            for (int j = 0; j < 4; ++j)
                acc[i][j] = __builtin_amdgcn_mfma_f32_16x16x32_bf16(af[i], bfr[j], acc[i][j], 0, 0, 0);
    };

    const int T = K >> 5;
    stage(0);
    stage(16384);
    int oc = 0, on = 16384, on2 = 32768;
    for (int kt = 0; kt < T - 2; ++kt){
        asm volatile("s_waitcnt vmcnt(4)" ::: "memory");
        __builtin_amdgcn_s_barrier();
        asm volatile("" ::: "memory");
        stage(on2);
        compute(oc);
        int tmp = oc; oc = on; on = on2; on2 = tmp;
    }
    asm volatile("s_waitcnt vmcnt(4)" ::: "memory");
    __builtin_amdgcn_s_barrier();
    asm volatile("" ::: "memory");
    compute(oc);
    { int tmp = oc; oc = on; on = on2; on2 = tmp; }
    asm volatile("s_waitcnt vmcnt(0)" ::: "memory");
    __builtin_amdgcn_s_barrier();
    asm volatile("" ::: "memory");
    compute(oc);
    __syncthreads();

    if constexpr (EPI == 2){
        const int lr = ko*4;
        #pragma unroll
        for (int j = 0; j < 4; ++j){
            int gcol = bx*128 + ncol + j*16 + lf;
            float bv = bias[gcol];
            #pragma unroll
            for (int i = 0; i < 4; ++i){
                #pragma unroll
                for (int r = 0; r < 4; ++r){
                    size_t grow = (size_t)by*128 + mrow + i*16 + lr + r;
                    float v = acc[i][j][r] + bv + x2[grow*ldc + gcol];
                    store_out(&C[grow*ldc + gcol], v);
                }
            }
        }
    } else {
        short* cs = CsBase + w*(64*72);
        const int odd = lf & 1;
        const int rsel = odd*2;
        #pragma unroll
        for (int j = 0; j < 4; ++j){
            float bv = bias[bx*128 + ncol + j*16 + lf];
            #pragma unroll
            for (int i = 0; i < 4; ++i){
                float vv0 = acc[i][j][0] + bv;
                float vv1 = acc[i][j][1] + bv;
                float vv2 = acc[i][j][2] + bv;
                float vv3 = acc[i][j][3] + bv;
                if constexpr (EPI == 1){
                    vv0 = gelu_f(vv0); vv1 = gelu_f(vv1);
                    vv2 = gelu_f(vv2); vv3 = gelu_f(vv3);
                }
                unsigned long long self = (unsigned long long)pk_bf16(vv0, vv1)
                                        | ((unsigned long long)pk_bf16(vv2, vv3) << 32);
                unsigned long long nbr = __shfl_xor(self, 1);
                unsigned long long lo = odd ? nbr : self;
                unsigned long long hi = odd ? self : nbr;
                int colb = 16*j + (lf & ~1);
                unsigned int w0 = (unsigned int)((lo >> (16*rsel)) & 0xffffu)
                                | ((unsigned int)((hi >> (16*rsel)) & 0xffffu) << 16);
                unsigned int w1 = (unsigned int)((lo >> (16*(rsel+1))) & 0xffffu)
                                | ((unsigned int)((hi >> (16*(rsel+1))) & 0xffffu) << 16);
                *(unsigned int*)(cs + (16*i + 4*ko + rsel    )*72 + colb) = w0;
                *(unsigned int*)(cs + (16*i + 4*ko + rsel + 1)*72 + colb) = w1;
            }
        }
        const int subrow = lane >> 3, cq = lane & 7;
        #pragma unroll
        for (int rr = 0; rr < 8; ++rr){
            int rl = rr*8 + subrow;
            short8 vv = *(const short8*)(cs + rl*72 + cq*8);
            size_t grow = (size_t)by*128 + mrow + rl;
            int gcol = bx*128 + ncol + cq*8;
            *(short8*)((short*)C + grow*ldc + gcol) = vv;
        }
    }
}

// ---------------------------------------------------------------------------
// merge A (kept, −ve proven): LN1 + prep in one launch. Block ranges:
// [0,16384) = LN1 rows; [16384,19008) = selmap init + 3 weight converts.
// ---------------------------------------------------------------------------
__global__ __launch_bounds__(256) void ln1_prep_kernel(const float* __restrict__ x,
                                                       const float* __restrict__ g,
                                                       const float* __restrict__ bt,
                                                       float* __restrict__ xn,
                                                       bf16* __restrict__ xnb,
                                                       const float* __restrict__ in_w,
                                                       const float* __restrict__ w1,
                                                       const float* __restrict__ w2,
                                                       bf16* __restrict__ kvw_b,
                                                       bf16* __restrict__ w1_b,
                                                       bf16* __restrict__ w2_b,
                                                       int* __restrict__ selmap)
{
    __shared__ double sbuf[8];
    int bid = blockIdx.x, t = threadIdx.x;
    if (bid >= MROWS){
        int pb = bid - MROWS;
        if (pb < 64){
            selmap[pb*256 + t] = -1;
            return;
        }
        const float* src; bf16* dst; int i;
        if (pb < 576){       src = in_w + (size_t)DIM*DIM; dst = kvw_b; i = ((pb - 64)*256 + t)*4; }
        else if (pb < 1600){ src = w1;  dst = w1_b; i = ((pb - 576)*256 + t)*4; }
        else {               src = w2;  dst = w2_b; i = ((pb - 1600)*256 + t)*4; }
        float4 v = *(const float4*)(src + i);
        dst[i+0] = __float2bfloat16(v.x);
        dst[i+1] = __float2bfloat16(v.y);
        dst[i+2] = __float2bfloat16(v.z);
        dst[i+3] = __float2bfloat16(v.w);
        return;
    }
    int row = bid;
    size_t base = (size_t)row*DIM;
    double x0 = (double)x[base + t];
    double x1 = (double)x[base + t + 256];
    double a = x0 + x1, q = x0*x0 + x1*x1;
    #pragma unroll
    for (int off = 32; off > 0; off >>= 1){
        a += __shfl_down(a, off);
        q += __shfl_down(q, off);
    }
    if ((t & 63) == 0){ sbuf[t >> 6] = a; sbuf[4 + (t >> 6)] = q; }
    __syncthreads();
    double sx  = sbuf[0] + sbuf[1] + sbuf[2] + sbuf[3];
    double sxx = sbuf[4] + sbuf[5] + sbuf[6] + sbuf[7];
    double m   = sx*(1.0/DIM);
    double var = sxx*(1.0/DIM) - m*m;
    double r = 1.0/sqrt(var + 1e-5);
    double y0 = (x0 - m)*r*(double)g[t]     + (double)bt[t];
    double y1 = (x1 - m)*r*(double)g[t+256] + (double)bt[t+256];
    xn[base+t] = (float)y0;       xn[base+t+256] = (float)y1;
    xnb[base+t] = __float2bfloat16((float)y0);
    xnb[base+t+256] = __float2bfloat16((float)y1);
}

// ---------------------------------------------------------------------------
// merge B (kept, −ve proven): KV projection GEMM (blocks [0,1024)) + xbar
// column-sum partials (blocks [1024,1280), 2 cols/thread).
// ---------------------------------------------------------------------------
__global__ __launch_bounds__(256, 3) void kv_xbar_kernel(const bf16* __restrict__ A,
                                                         const bf16* __restrict__ Bm,
                                                         const float* __restrict__ bias,
                                                         bf16* __restrict__ Khm,
                                                         bf16* __restrict__ Vhm,
                                                         const float* __restrict__ xn,
                                                         double* __restrict__ xbpart)
{
    __shared__ __align__(16) char smem[49152];
    const int t = threadIdx.x;
    if (blockIdx.x >= 1024){
        int cid = blockIdx.x - 1024;          // 0..255
        int b = cid >> 5, c = cid & 31;
        const float* p = xn + ((size_t)b*SEQ + c*64)*DIM + t;
        double s0 = 0.0, s1 = 0.0;
        #pragma unroll 8
        for (int i = 0; i < 64; ++i){
            s0 += (double)p[(size_t)i*DIM];
            s1 += (double)p[(size_t)i*DIM + 256];
        }
        xbpart[((size_t)(b*32 + c))*DIM + t]       = s0;
        xbpart[((size_t)(b*32 + c))*DIM + t + 256] = s1;
        return;
    }
    short* CsBase = (short*)smem;
    const int K = DIM;                        // 512, T = 16
    const int bid = blockIdx.x;
    const int per = 128;                      // 1024 gemm blocks / 8 XCDs
    const int lid = (bid & 7)*per + (bid >> 3);
    const int bx  = lid & 7;                  // lgGX = 3
    const int by  = lid >> 3;

    const int lane = t & 63;
    const int w    = t >> 6;
    const int lf   = lane & 15;
    const int ko   = lane >> 4;
    const int slot = ko ^ ((lf >> 1) & 3);
    const int mrow = (w >> 1)*64, ncol = (w & 1)*64;

    floatx4 acc[4][4];
    floatx4 z = {0.f,0.f,0.f,0.f};
    #pragma unroll
    for (int i = 0; i < 4; ++i)
        #pragma unroll
        for (int j = 0; j < 4; ++j) acc[i][j] = z;

    const int srow = w*16 + (lane >> 2);
    const int sq   = lane & 3;
    const int r0 = srow,      kq0 = sq ^ ((r0 >> 1) & 3);
    const int r1 = 64 + srow, kq1 = sq ^ ((r1 >> 1) & 3);
    const short* ga0 = (const short*)A  + ((size_t)by*128 + r0)*K + kq0*8;
    const short* ga1 = (const short*)A  + ((size_t)by*128 + r1)*K + kq1*8;
    const short* gb0 = (const short*)Bm + ((size_t)bx*128 + r0)*K + kq0*8;
    const short* gb1 = (const short*)Bm + ((size_t)bx*128 + r1)*K + kq1*8;
    char* la0 = smem + w*1024;
    char* la1 = smem + 4096 + w*1024;
    char* lb0 = smem + 8192 + w*1024;
    char* lb1 = smem + 12288 + w*1024;

    auto stage = [&](int off){
        load_lds16(ga0, la0 + off); load_lds16(ga1, la1 + off);
        load_lds16(gb0, lb0 + off); load_lds16(gb1, lb1 + off);
        ga0 += 32; ga1 += 32; gb0 += 32; gb1 += 32;
    };
    auto compute = [&](int off){
        const short* As = (const short*)(smem + off);
        const short* Bs = (const short*)(smem + off + 8192);
        short8 af[4], bfr[4];
        #pragma unroll
        for (int i = 0; i < 4; ++i){
            af[i]  = *(const short8*)(As + (mrow + i*16 + lf)*32 + slot*8);
            bfr[i] = *(const short8*)(Bs + (ncol + i*16 + lf)*32 + slot*8);
        }
        #pragma unroll
        for (int i = 0; i < 4; ++i)
            #pragma unroll
            for (int j = 0; j < 4; ++j)
                acc[i][j] = __builtin_amdgcn_mfma_f32_16x16x32_bf16(af[i], bfr[j], acc[i][j], 0, 0, 0);
    };

    const int T = K >> 5;
    stage(0);
    stage(16384);
    int oc = 0, on = 16384, on2 = 32768;
    for (int kt = 0; kt < T - 2; ++kt){
        asm volatile("s_waitcnt vmcnt(4)" ::: "memory");
        __builtin_amdgcn_s_barrier();
        asm volatile("" ::: "memory");
        stage(on2);
        compute(oc);
        int tmp = oc; oc = on; on = on2; on2 = tmp;
    }
    asm volatile("s_waitcnt vmcnt(4)" ::: "memory");
    __builtin_amdgcn_s_barrier();
    asm volatile("" ::: "memory");
    compute(oc);
    { int tmp = oc; oc = on; on = on2; on2 = tmp; }
    asm volatile("s_waitcnt vmcnt(0)" ::: "memory");
    __builtin_amdgcn_s_barrier();
    asm volatile("" ::: "memory");
    compute(oc);
    __syncthreads();

    // epilogue: bf16 pack -> LDS stage -> coalesced head-major K/V scatter
    short* cs = CsBase + w*(64*72);
    const int odd = lf & 1;
    const int rsel = odd*2;
    #pragma unroll
    for (int j = 0; j < 4; ++j){
        float bv = bias[bx*128 + ncol + j*16 + lf];
        #pragma unroll
        for (int i = 0; i < 4; ++i){
            float vv0 = acc[i][j][0] + bv;
            float vv1 = acc[i][j][1] + bv;
            float vv2 = acc[i][j][2] + bv;
            float vv3 = acc[i][j][3] + bv;
            unsigned long long self = (unsigned long long)pk_bf16(vv0, vv1)
                                    | ((unsigned long long)pk_bf16(vv2, vv3) << 32);
            unsigned long long nbr = __shfl_xor(self, 1);
            unsigned long long lo = odd ? nbr : self;
            unsigned long long hi = odd ? self : nbr;
            int colb = 16*j + (lf & ~1);
            unsigned int w0 = (unsigned int)((lo >> (16*rsel)) & 0xffffu)
                            | ((unsigned int)((hi >> (16*rsel)) & 0xffffu) << 16);
            unsigned int w1 = (unsigned int)((lo >> (16*(rsel+1))) & 0xffffu)
                            | ((unsigned int)((hi >> (16*(rsel+1))) & 0xffffu) << 16);
            *(unsigned int*)(cs + (16*i + 4*ko + rsel    )*72 + colb) = w0;
            *(unsigned int*)(cs + (16*i + 4*ko + rsel + 1)*72 + colb) = w1;
        }
    }
    const int subrow = lane >> 3, cq = lane & 7;
    #pragma unroll
    for (int rr = 0; rr < 8; ++rr){
        int rl = rr*8 + subrow;
        short8 vv = *(const short8*)(cs + rl*72 + cq*8);
        int grow = by*128 + mrow + rl;        // b*SEQ + s
        int b = grow >> 11, s = grow & 2047;
        int gc = bx*128 + ncol + cq*8;
        int h = (gc >> 6) & 7, d = gc & 63;
        bf16* dst = (gc < 512) ? Khm : Vhm;
        *(short8*)((short*)dst + (((size_t)(b*NH + h))*SEQ + s)*DHEAD + d) = vv;
    }
}

__global__ __launch_bounds__(512) void xbar_fin_kernel(const double* __restrict__ part,
                                                       double* __restrict__ xbar_d,
                                                       float* __restrict__ xbar_f){
    int b = blockIdx.x, d = threadIdx.x;
    double s = 0.0;
    for (int c = 0; c < 32; ++c) s += part[((size_t)(b*32 + c))*DIM + d];
    s *= (1.0/SEQ);
    xbar_d[(size_t)b*DIM + d] = s;
    xbar_f[(size_t)b*DIM + d] = (float)s;
}

// sparsity*sqrt(D) = Σxn² - dot(xn_row, xbar); fp64 over the SAME fp32 xn
// values ref uses -> ranking margin >> ref's own fp32 noise.
__global__ __launch_bounds__(256) void sparsity_kernel(const float* __restrict__ xn,
                                                       const double* __restrict__ xbar,
                                                       double* __restrict__ sp)
{
    int row  = blockIdx.x*4 + (threadIdx.x >> 6);
    int lane = threadIdx.x & 63;
    int b    = row >> 11;
    const float* xr = xn + (size_t)row*DIM;
    const double* xb = xbar + (size_t)b*DIM;
    double s = 0.0, d2 = 0.0;
    for (int e = lane; e < DIM; e += 64){
        double xv = (double)xr[e];
        s  += xv*xb[e];
        d2 += xv*xv;
    }
    #pragma unroll
    for (int off = 32; off > 0; off >>= 1){
        s  += __shfl_down(s, off);
        d2 += __shfl_down(d2, off);
    }
    if (lane == 0) sp[row] = d2 - s;
}

// ---------------------------------------------------------------------------
// register-resident top-39 (proven): packed monotone u64 order keys.
// ---------------------------------------------------------------------------
__global__ __launch_bounds__(256) void topk_kernel(const double* __restrict__ sp,
                                                   int* __restrict__ topidx,
                                                   int* __restrict__ selmap,
                                                   float* __restrict__ dout)
{
    __shared__ unsigned long long wmax[4];
    int b = blockIdx.x, t = threadIdx.x;
    int lane = t & 63, w = t >> 6;

    unsigned long long pk[8];
    #pragma unroll
    for (int i = 0; i < 8; ++i){
        int idx = i*256 + t;                          // coalesced
        unsigned long long bits =
            (unsigned long long)__double_as_longlong(sp[(size_t)b*SEQ + idx]);
        unsigned long long m = (bits & 0x8000000000000000ull)
                             ? ~bits : (bits | 0x8000000000000000ull);
        pk[i] = (m & ~2047ull) | (unsigned long long)(2047 - idx);
    }
    unsigned long long lm = pk[0];
    #pragma unroll
    for (int i = 1; i < 8; ++i) lm = (pk[i] > lm) ? pk[i] : lm;

    for (int it = 0; it < TOPQ; ++it){
        unsigned long long m = lm;
        #pragma unroll
        for (int off = 32; off > 0; off >>= 1){
            unsigned long long o = __shfl_xor(m, off);
            m = (o > m) ? o : m;
        }
        if (lane == 0) wmax[w] = m;
        __syncthreads();
        unsigned long long g01 = (wmax[0] > wmax[1]) ? wmax[0] : wmax[1];
        unsigned long long g23 = (wmax[2] > wmax[3]) ? wmax[2] : wmax[3];
        unsigned long long g = (g01 > g23) ? g01 : g23;
        int idx = 2047 - (int)(g & 2047ull);
        if (t == 0){
            topidx[b*64 + it] = idx;
            selmap[(size_t)b*SEQ + idx] = it;
        }
        if ((idx & 255) == t){                        // owner removes + recompute
            int slot = idx >> 8;
            #pragma unroll
            for (int i = 0; i < 8; ++i) if (i == slot) pk[i] = 0;
            lm = pk[0];
            #pragma unroll
            for (int i = 1; i < 8; ++i) lm = (pk[i] > lm) ? pk[i] : lm;
        }
        __syncthreads();                              // wmax reuse safety
    }
    if (b == 0 && t == 0) dout[(size_t)MROWS*DIM] = (float)TOPQ/(float)SEQ;
}

// ---------------------------------------------------------------------------
// qproj v2: 32x-parallel (proven). grid (32, QPAD, BATCH).
// ---------------------------------------------------------------------------
__global__ __launch_bounds__(256) void qproj_kernel(const float* __restrict__ xn,
                                                    const float* __restrict__ in_w,
                                                    const float* __restrict__ in_b,
                                                    const int* __restrict__ topidx,
                                                    bf16* __restrict__ Qhm)
{
    __shared__ float qr[DIM];
    int dblk = blockIdx.x, j = blockIdx.y, b = blockIdx.z;
    int t = threadIdx.x;
    int o = t >> 4, ks = t & 15;
    int d0 = dblk*16 + o;
    int h = d0 >> 6, d = d0 & 63;
    if (j >= TOPQ){
        if (ks == 0)
            Qhm[((size_t)(b*NH + h)*QPAD + j)*DHEAD + d] = __float2bfloat16(0.f);
        return;
    }
    int srow = topidx[b*64 + j];
    const float* xr = xn + ((size_t)(b*SEQ + srow))*DIM;
    qr[t] = xr[t]; qr[t + 256] = xr[t + 256];
    __syncthreads();
    const float* wr = in_w + (size_t)d0*DIM;
    float s = 0.f;
    #pragma unroll
    for (int i = 0; i < 8; ++i){
        int e = i*64 + ks*4;
        float4 wv = *(const float4*)(wr + e);
        float4 cv = *(const float4*)(qr + e);
        s += cv.x*wv.x + cv.y*wv.y + cv.z*wv.z + cv.w*wv.w;
    }
    #pragma unroll
    for (int off = 8; off > 0; off >>= 1) s += __shfl_down(s, off, 16);
    if (ks == 0)
        Qhm[((size_t)(b*NH + h)*QPAD + j)*DHEAD + d] = __float2bfloat16(s + in_b[d0]);
}

// ---------------------------------------------------------------------------
// MFMA split-K attention partial (KC=64, 2 blocks/CU).
// ---------------------------------------------------------------------------
__global__ __launch_bounds__(256, 1) void attn_mfma_kernel(const bf16* __restrict__ Qhm,
                                                           const bf16* __restrict__ Khm,
                                                           const bf16* __restrict__ Vhm,
                                                           float* __restrict__ part)
{
    __shared__ __align__(16) short vsm[4*4096];   // 32 KB: 4 waves x (64k x 64d)
    const int bh   = blockIdx.z*NH + blockIdx.y;
    const int w    = threadIdx.x >> 6;
    const int lane = threadIdx.x & 63;
    const int ch   = blockIdx.x*4 + w;           // chunk 0..31
    const int kb   = ch*KC;                      // first key of chunk
    const int lf   = lane & 15;
    const int g    = lane >> 4;

    short* vbase = vsm + w*4096;
    const short* vg = (const short*)Vhm + ((size_t)bh*SEQ + kb)*DHEAD;
    {
        const int kh = lane >> 1, dh = (lane & 1)*8;
        #pragma unroll
        for (int L = 0; L < 8; ++L){
            int k = (L & 1)*32 + kh;
            int d = (L >> 1)*16 + dh;
            load_lds16(vg + (size_t)k*DHEAD + d, vbase + L*512);
        }
    }

    short8 qf[3][2];
    const short* qp = (const short*)Qhm + (size_t)bh*QPAD*DHEAD;
    #pragma unroll
    for (int nt = 0; nt < 3; ++nt)
        #pragma unroll
        for (int s = 0; s < 2; ++s)
            qf[nt][s] = *(const short8*)(qp + (nt*16 + lf)*DHEAD + s*32 + g*8);

    floatx4 sa[4][3];
    floatx4 z = {0.f,0.f,0.f,0.f};
    #pragma unroll
    for (int mt = 0; mt < 4; ++mt)
        #pragma unroll
        for (int nt = 0; nt < 3; ++nt) sa[mt][nt] = z;

    const short* kp = (const short*)Khm + ((size_t)bh*SEQ + kb)*DHEAD;
    #pragma unroll
    for (int mt = 0; mt < 4; ++mt){
        const short* kr = kp + (size_t)(mt*16 + lf)*DHEAD + g*8;
        short8 kf0 = *(const short8*)(kr);
        short8 kf1 = *(const short8*)(kr + 32);
        #pragma unroll
        for (int nt = 0; nt < 3; ++nt){
            sa[mt][nt] = __builtin_amdgcn_mfma_f32_16x16x32_bf16(kf0, qf[nt][0], sa[mt][nt], 0, 0, 0);
            sa[mt][nt] = __builtin_amdgcn_mfma_f32_16x16x32_bf16(kf1, qf[nt][1], sa[mt][nt], 0, 0, 0);
        }
    }

    float mx[3], ls[3];
    #pragma unroll
    for (int nt = 0; nt < 3; ++nt){
        float m = sa[0][nt][0];
        #pragma unroll
        for (int mt = 0; mt < 4; ++mt)
            #pragma unroll
            for (int r = 0; r < 4; ++r) m = fmaxf(m, sa[mt][nt][r]);
        m = fmaxf(m, __shfl_xor(m, 16));
        m = fmaxf(m, __shfl_xor(m, 32));
        float l = 0.f;
        #pragma unroll
        for (int mt = 0; mt < 4; ++mt){
            #pragma unroll
            for (int r = 0; r < 4; ++r){
                float p = __expf((sa[mt][nt][r] - m)*0.125f);   // 1/sqrt(64)
                sa[mt][nt][r] = p;
                l += p;
            }
        }
        l += __shfl_xor(l, 16);
        l += __shfl_xor(l, 32);
        mx[nt] = m; ls[nt] = l;
    }

    asm volatile("s_waitcnt vmcnt(0)" ::: "memory");   // V staging landed
    floatx4 oacc[3][4];
    #pragma unroll
    for (int mi = 0; mi < 3; ++mi)
        #pragma unroll
        for (int dt = 0; dt < 4; ++dt) oacc[mi][dt] = z;

    #pragma unroll
    for (int t = 0; t < 4; ++t){
        sh4 pa[3];
        #pragma unroll
        for (int mi = 0; mi < 3; ++mi){
            union { sh4 v; unsigned u[2]; } pk;
            pk.u[0] = pk_bf16(sa[t][mi][0], sa[t][mi][1]);
            pk.u[1] = pk_bf16(sa[t][mi][2], sa[t][mi][3]);
            pa[mi] = pk.v;
        }
        #pragma unroll
        for (int dt = 0; dt < 4; ++dt){
            sh4 vf = tr16_read(vbase + dt*1024 + (t*16 + 4*g)*16 + lf);
            #pragma unroll
            for (int mi = 0; mi < 3; ++mi)
                oacc[mi][dt] = mfma16(pa[mi], vf, oacc[mi][dt]);
        }
    }

    float* pbase = part + ((size_t)bh*TOPQ*NKC + ch)*PSTR;
    #pragma unroll
    for (int mi = 0; mi < 3; ++mi){
        #pragma unroll
        for (int r = 0; r < 4; ++r){
            int q = mi*16 + 4*g + r;
            if (q < TOPQ){
                float* pp = pbase + (size_t)q*NKC*PSTR;
                #pragma unroll
                for (int dt = 0; dt < 4; ++dt)
                    pp[dt*16 + lf] = oacc[mi][dt][r];
            }
        }
    }
    #pragma unroll
    for (int nt = 0; nt < 3; ++nt){
        int q = nt*16 + lf;
        if (g == 3 && q < TOPQ){
            float* pp = pbase + (size_t)q*NKC*PSTR;
            pp[64] = mx[nt]*0.125f;
            pp[65] = ls[nt];
        }
    }
}

// pass 2 (REVERTED from merge C: redundant 32x apart reads missed XCD-local
// L2 -> 83 MB HBM fetch, 110us. Separate reduce reads apart ONCE.): merge 32
// partials per (b,h,q); wave per (q,h), 4 q per block -> ctxb.
__global__ __launch_bounds__(256) void attn_reduce_kernel(const float* __restrict__ part,
                                                          float* __restrict__ ctx)
{
    int qc = blockIdx.x, h = blockIdx.y, b = blockIdx.z;
    int w = threadIdx.x >> 6, lane = threadIdx.x & 63;
    int q = qc*4 + w;
    if (q >= TOPQ) return;
    const float* pb = part + (((size_t)(b*NH + h))*TOPQ + q)*NKC*PSTR;
    float M = -3.402823466e38f;
    #pragma unroll
    for (int i = 0; i < NKC; ++i) M = fmaxf(M, pb[i*PSTR + 64]);
    float L = 0.f, a = 0.f;
    #pragma unroll
    for (int i = 0; i < NKC; ++i){
        float sc = __expf(pb[i*PSTR + 64] - M);
        L += pb[i*PSTR + 65]*sc;
        a += pb[i*PSTR + lane]*sc;
    }
    ctx[((size_t)(b*TOPQ + q))*DIM + h*DHEAD + lane] = a/L;
}

// ---------------------------------------------------------------------------
// outproj v2: 32x-parallel (proven round-16).
// ---------------------------------------------------------------------------
__global__ __launch_bounds__(256) void outproj_kernel(const float* __restrict__ ctx,
                                                      const float* __restrict__ ow,
                                                      const float* __restrict__ ob,
                                                      float* __restrict__ sout)
{
    __shared__ float cr[DIM];
    int dblk = blockIdx.x, q = blockIdx.y, b = blockIdx.z;
    int t = threadIdx.x;
    const float* xr = ctx + ((size_t)(b*TOPQ + q))*DIM;
    cr[t] = xr[t]; cr[t + 256] = xr[t + 256];
    __syncthreads();
    int o = t >> 4, ks = t & 15;
    int d0 = dblk*16 + o;
    const float* wr = ow + (size_t)d0*DIM;
    float s = 0.f;
    #pragma unroll
    for (int i = 0; i < 8; ++i){
        int e = i*64 + ks*4;
        float4 wv = *(const float4*)(wr + e);
        float4 cv = *(const float4*)(cr + e);
        s += cv.x*wv.x + cv.y*wv.y + cv.z*wv.z + cv.w*wv.w;
    }
    #pragma unroll
    for (int off = 8; off > 0; off >>= 1) s += __shfl_down(s, off, 16);
    if (ks == 0) sout[((size_t)(b*TOPQ + q))*DIM + d0] = s + ob[d0];
}

// ---------------------------------------------------------------------------
// res+LN2: ONE-PASS paired fp32 reduction (Σv, Σv²); 1 barrier.
// ---------------------------------------------------------------------------
__global__ __launch_bounds__(256) void res_ln2_kernel(const float* __restrict__ x,
                                                      const float* __restrict__ xbar,
                                                      const float* __restrict__ sout,
                                                      const int* __restrict__ selmap,
                                                      const float* __restrict__ g2,
                                                      const float* __restrict__ bt2,
                                                      float* __restrict__ x2,
                                                      bf16* __restrict__ hb)
{
    __shared__ float sbuf[8];
    int row = blockIdx.x;
    int b = row >> 11;
    int t = threadIdx.x;
    int slot = selmap[row];
    const float* ar = (slot >= 0) ? (sout + ((size_t)(b*TOPQ + slot))*DIM)
                                  : (xbar + (size_t)b*DIM);
    size_t base = (size_t)row*DIM;
    float v0 = x[base + t]       + ar[t];
    float v1 = x[base + t + 256] + ar[t + 256];
    x2[base + t] = v0; x2[base + t + 256] = v1;
    float a = v0 + v1, q = v0*v0 + v1*v1;
    #pragma unroll
    for (int off = 32; off > 0; off >>= 1){
        a += __shfl_down(a, off);
        q += __shfl_down(q, off);
    }
    if ((t & 63) == 0){ sbuf[t >> 6] = a; sbuf[4 + (t >> 6)] = q; }
    __syncthreads();
    float sv  = sbuf[0] + sbuf[1] + sbuf[2] + sbuf[3];
    float svv = sbuf[4] + sbuf[5] + sbuf[6] + sbuf[7];
    float m   = sv*(1.f/DIM);
    float var = svv*(1.f/DIM) - m*m;
    float r = 1.f/sqrtf(var + 1e-5f);
    hb[base + t]       = __float2bfloat16((v0 - m)*r*g2[t]     + bt2[t]);
    hb[base + t + 256] = __float2bfloat16((v1 - m)*r*g2[t+256] + bt2[t+256]);
}

// ---------------------------------------------------------------------------
extern "C" void kernel_launch(void* const* d_in, const int* in_sizes, int n_in,
                              void* d_out, int out_size, void* d_ws, size_t ws_size,
                              hipStream_t stream)
{
    (void)in_sizes; (void)n_in; (void)out_size; (void)ws_size;
    const float* x     = (const float*)d_in[0];
    const float* ln1_g = (const float*)d_in[1];
    const float* ln1_b = (const float*)d_in[2];
    const float* in_w  = (const float*)d_in[3];
    const float* in_b  = (const float*)d_in[4];
    const float* out_w = (const float*)d_in[5];
    const float* out_b = (const float*)d_in[6];
    const float* ln2_g = (const float*)d_in[7];
    const float* ln2_b = (const float*)d_in[8];
    const float* w1    = (const float*)d_in[9];
    const float* b1    = (const float*)d_in[10];
    const float* w2    = (const float*)d_in[11];
    const float* b2    = (const float*)d_in[12];
    float* out = (float*)d_out;

    const size_t MB = 1024*1024;
    char* base = (char*)d_ws;
    float* xn_f  = (float*)base;                 // [0,32MiB); reused as x2_f later
    bf16*  xn_b  = (bf16*)(base + 32*MB);        // dead after kv-gemm -> h_b
    bf16*  Khm   = (bf16*)(base + 48*MB);
    bf16*  Vhm   = (bf16*)(base + 64*MB);
    bf16*  h_b   = (bf16*)(base + 32*MB);
    bf16*  h1_b  = (bf16*)(base + 48*MB);        // overwrites Khm/Vhm after attn
    float* x2_f  = xn_f;
    // apart (21 MiB) lives at [80,101) MiB: free during attention (h1_b rows
    // covering it are written only by FFN1, after attn_reduce consumed apart).
    float* apart = (float*)(base + 80*MB);
    char* p = base + 112*MB;
    bf16*  kvw_b  = (bf16*)p;  p += (size_t)1024*DIM*2;        // in_w rows [512,1536) bf16
    bf16*  w1_b   = (bf16*)p;  p += (size_t)FFD*DIM*2;
    bf16*  w2_b   = (bf16*)p;  p += (size_t)DIM*FFD*2;
    double* xbpart= (double*)p; p += (size_t)BATCH*32*DIM*8;
    double* xbar_d= (double*)p; p += (size_t)BATCH*DIM*8;
    float* xbar_f = (float*)p;  p += (size_t)BATCH*DIM*4;
    double* spars = (double*)p; p += (size_t)MROWS*8;
    int*   topidx = (int*)p;    p += (size_t)BATCH*64*4;
    int*   selmap = (int*)p;    p += (size_t)MROWS*4;
    bf16*  Qhm    = (bf16*)p;   p += (size_t)BATCH*NH*QPAD*DHEAD*2;   // 384 KiB
    float* ctxb   = (float*)p;  p += (size_t)BATCH*TOPQ*DIM*4;
    float* sout   = (float*)p;  p += (size_t)BATCH*TOPQ*DIM*4;

    // 12 dispatches: merges A,B kept (-17us); merge C reverted (+92us HBM).
    ln1_prep_kernel<<<MROWS + 2624, 256, 0, stream>>>(
        x, ln1_g, ln1_b, xn_f, xn_b, in_w, w1, w2, kvw_b, w1_b, w2_b, selmap);
    kv_xbar_kernel<<<1280, 256, 0, stream>>>(
        xn_b, kvw_b, in_b + DIM, Khm, Vhm, xn_f, xbpart);
    xbar_fin_kernel<<<BATCH, 512, 0, stream>>>(xbpart, xbar_d, xbar_f);
    sparsity_kernel<<<MROWS/4, 256, 0, stream>>>(xn_f, xbar_d, spars);
    topk_kernel<<<BATCH, 256, 0, stream>>>(spars, topidx, selmap, out);
    qproj_kernel<<<dim3(32, QPAD, BATCH), 256, 0, stream>>>(xn_f, in_w, in_b, topidx, Qhm);
    attn_mfma_kernel<<<dim3(NKC/4, NH, BATCH), 256, 0, stream>>>(Qhm, Khm, Vhm, apart);
    attn_reduce_kernel<<<dim3((TOPQ + 3)/4, NH, BATCH), 256, 0, stream>>>(apart, ctxb);
    outproj_kernel<<<dim3(32, TOPQ, BATCH), 256, 0, stream>>>(ctxb, out_w, out_b, sout);
    res_ln2_kernel<<<MROWS, 256, 0, stream>>>(x, xbar_f, sout, selmap, ln2_g, ln2_b, x2_f, h_b);
    // FFN1: grid 16x128 -> 2048 blocks, lgGX=4
    gemm128_kernel<1, bf16><<<2048, 256, 0, stream>>>(
        h_b, w1_b, b1, h1_b, nullptr, nullptr, DIM, FFD, 4);
    // FFN2: grid 4x128 -> 512 blocks, lgGX=2
    gemm128_kernel<2, float><<<512, 256, 0, stream>>>(
        h1_b, w2_b, b2, out, x2_f, nullptr, FFD, DIM, 2);
}

// Round 13
// 348.600 us; speedup vs baseline: 1.2403x; 1.0129x over previous
//
#include <hip/hip_runtime.h>
#include <hip/hip_bf16.h>
#include <math.h>

#define BATCH 8
#define SEQ   2048
#define DIM   512
#define NH    8
#define DHEAD 64
#define FFD   2048
#define TOPQ  39            // ceil(5*ln(2048)) with factor=5, min_k=5 (fixed harness inputs)
#define MROWS (BATCH*SEQ)   // 16384
#define KC    64            // keys per attention partial chunk (one wave)
#define NKC   (SEQ/KC)      // 32
#define PSTR  66            // partial stride: 64 ctx + m + l
#define QPAD  48            // TOPQ padded to 3 MFMA row-tiles

typedef __hip_bfloat16 bf16;
typedef __attribute__((ext_vector_type(8))) short short8;
typedef __attribute__((ext_vector_type(4))) short sh4;
typedef __attribute__((ext_vector_type(4))) float floatx4;

__device__ __forceinline__ float bf2f(short u){
    return __uint_as_float(((unsigned int)(unsigned short)u) << 16);
}
// pack 2 floats -> 2 bf16 (RNE) in one u32 via intrinsic casts (fast path).
__device__ __forceinline__ unsigned int pk_bf16(float a, float b){
    union { bf16 h; unsigned short u; } ca, cb;
    ca.h = __float2bfloat16(a); cb.h = __float2bfloat16(b);
    return (unsigned int)ca.u | ((unsigned int)cb.u << 16);
}
// fast gelu, sigmoid form: v*sigmoid(2u); rcp ~1ulp << bf16 rounding.
__device__ __forceinline__ float gelu_f(float v){
    float u = v*(0.7978845608028654f + 0.0356774081363f*v*v);
    float e = __expf(-2.f*u);
    return v*__builtin_amdgcn_rcpf(1.f + e);
}

// async global->LDS, 16 B per lane; LDS dest = wave-uniform base + lane*16
__device__ __forceinline__ void load_lds16(const void* g, void* l){
    auto gp = reinterpret_cast<const uint32_t __attribute__((address_space(1)))*>(
        reinterpret_cast<uintptr_t>(g));
    auto lp = reinterpret_cast<uint32_t __attribute__((address_space(3)))*>(
        reinterpret_cast<uintptr_t>(l));
    __builtin_amdgcn_global_load_lds(gp, lp, 16, 0, 0);
}

// 16x16x16 bf16 MFMA (K=16): A/B = 4 bf16/lane, C/D std 16x16 map
__device__ __forceinline__ floatx4 mfma16(sh4 a, sh4 b, floatx4 c){
#if __has_builtin(__builtin_amdgcn_mfma_f32_16x16x16bf16_1k)
    return __builtin_amdgcn_mfma_f32_16x16x16bf16_1k(a, b, c, 0, 0, 0);
#elif __has_builtin(__builtin_amdgcn_mfma_f32_16x16x16_bf16)
    return __builtin_amdgcn_mfma_f32_16x16x16_bf16(a, b, c, 0, 0, 0);
#else
    asm volatile("v_mfma_f32_16x16x16_bf16 %0, %1, %2, %0\n\ts_nop 7\n\ts_nop 7"
                 : "+v"(c) : "v"(a), "v"(b));
    return c;
#endif
}

// transpose-read: 4 bf16 at elem strides {0,16,32,48} from per-lane LDS addr
__device__ __forceinline__ sh4 tr16_read(const short* p){
#if __has_builtin(__builtin_amdgcn_ds_read_tr16_b64_v4i16)
    auto lp = (__attribute__((address_space(3))) sh4*)(uintptr_t)p;
    return __builtin_amdgcn_ds_read_tr16_b64_v4i16(lp);
#elif __has_builtin(__builtin_amdgcn_ds_read_tr16_b64)
    auto lp = (__attribute__((address_space(3))) sh4*)(uintptr_t)p;
    return __builtin_amdgcn_ds_read_tr16_b64(lp);
#else
    sh4 r; r[0] = p[0]; r[1] = p[16]; r[2] = p[32]; r[3] = p[48]; return r;
#endif
}

__device__ __forceinline__ void store_out(bf16* p, float v){ *p = __float2bfloat16(v); }
__device__ __forceinline__ void store_out(float* p, float v){ *p = v; }

// ---------------------------------------------------------------------------
// 128x128-tile GEMM (proven): C = A(MxK)·B(NxK)^T + bias. Depth-2 pipeline,
// counted vmcnt. EPI: 1 = gelu->bf16 (FFN1), 2 = +x2 -> fp32 (FFN2).
// ---------------------------------------------------------------------------
template<int EPI, typename OUT_T>
__global__ __launch_bounds__(256, 3) void gemm128_kernel(const bf16* __restrict__ A,
                                                         const bf16* __restrict__ Bm,
                                                         const float* __restrict__ bias,
                                                         OUT_T* __restrict__ C,
                                                         const float* __restrict__ x2,
                                                         bf16* __restrict__ Vhm,
                                                         int K, int ldc, int lgGX)
{
    __shared__ __align__(16) char smem[49152];   // 3 x (As 8KB | Bs 8KB)
    short* CsBase = (short*)smem;

    const int bid = blockIdx.x;
    const int per = gridDim.x >> 3;
    const int lid = (bid & 7)*per + (bid >> 3);
    const int bx  = lid & ((1 << lgGX) - 1);
    const int by  = lid >> lgGX;

    const int t    = threadIdx.x;
    const int lane = t & 63;
    const int w    = t >> 6;
    const int lf   = lane & 15;
    const int ko   = lane >> 4;
    const int slot = ko ^ ((lf >> 1) & 3);
    const int mrow = (w >> 1)*64, ncol = (w & 1)*64;

    floatx4 acc[4][4];
    floatx4 z = {0.f,0.f,0.f,0.f};
    #pragma unroll
    for (int i = 0; i < 4; ++i)
        #pragma unroll
        for (int j = 0; j < 4; ++j) acc[i][j] = z;

    const int srow = w*16 + (lane >> 2);
    const int sq   = lane & 3;
    const int r0 = srow,      kq0 = sq ^ ((r0 >> 1) & 3);
    const int r1 = 64 + srow, kq1 = sq ^ ((r1 >> 1) & 3);
    const short* ga0 = (const short*)A  + ((size_t)by*128 + r0)*K + kq0*8;
    const short* ga1 = (const short*)A  + ((size_t)by*128 + r1)*K + kq1*8;
    const short* gb0 = (const short*)Bm + ((size_t)bx*128 + r0)*K + kq0*8;
    const short* gb1 = (const short*)Bm + ((size_t)bx*128 + r1)*K + kq1*8;
    char* la0 = smem + w*1024;
    char* la1 = smem + 4096 + w*1024;
    char* lb0 = smem + 8192 + w*1024;
    char* lb1 = smem + 12288 + w*1024;

    auto stage = [&](int off){
        load_lds16(ga0, la0 + off); load_lds16(ga1, la1 + off);
        load_lds16(gb0, lb0 + off); load_lds16(gb1, lb1 + off);
        ga0 += 32; ga1 += 32; gb0 += 32; gb1 += 32;
    };
    auto compute = [&](int off){
        const short* As = (const short*)(smem + off);
        const short* Bs = (const short*)(smem + off + 8192);
        short8 af[4], bfr[4];
        #pragma unroll
        for (int i = 0; i < 4; ++i){
            af[i]  = *(const short8*)(As + (mrow + i*16 + lf)*32 + slot*8);
            bfr[i] = *(const short8*)(Bs + (ncol + i*16 + lf)*32 + slot*8);
        }
        #pragma unroll
        for (int i = 0; i < 4; ++i)
            #pragma unroll
            for (int j = 0; j < 4; ++j)
                acc[i][j] = __builtin_amdgcn_mfma_f32_16x16x32_bf16(af[i], bfr[j], acc[i][j], 0, 0, 0);
    };

    const int T = K >> 5;
    stage(0);
    stage(16384);
    int oc = 0, on = 16384, on2 = 32768;
    for (int kt = 0; kt < T - 2; ++kt){
        asm volatile("s_waitcnt vmcnt(4)" ::: "memory");
        __builtin_amdgcn_s_barrier();
        asm volatile("" ::: "memory");
        stage(on2);
        compute(oc);
        int tmp = oc; oc = on; on = on2; on2 = tmp;
    }
    asm volatile("s_waitcnt vmcnt(4)" ::: "memory");
    __builtin_amdgcn_s_barrier();
    asm volatile("" ::: "memory");
    compute(oc);
    { int tmp = oc; oc = on; on = on2; on2 = tmp; }
    asm volatile("s_waitcnt vmcnt(0)" ::: "memory");
    __builtin_amdgcn_s_barrier();
    asm volatile("" ::: "memory");
    compute(oc);
    __syncthreads();

    if constexpr (EPI == 2){
        const int lr = ko*4;
        #pragma unroll
        for (int j = 0; j < 4; ++j){
            int gcol = bx*128 + ncol + j*16 + lf;
            float bv = bias[gcol];
            #pragma unroll
            for (int i = 0; i < 4; ++i){
                #pragma unroll
                for (int r = 0; r < 4; ++r){
                    size_t grow = (size_t)by*128 + mrow + i*16 + lr + r;
                    float v = acc[i][j][r] + bv + x2[grow*ldc + gcol];
                    store_out(&C[grow*ldc + gcol], v);
                }
            }
        }
    } else {
        short* cs = CsBase + w*(64*72);
        const int odd = lf & 1;
        const int rsel = odd*2;
        #pragma unroll
        for (int j = 0; j < 4; ++j){
            float bv = bias[bx*128 + ncol + j*16 + lf];
            #pragma unroll
            for (int i = 0; i < 4; ++i){
                float vv0 = acc[i][j][0] + bv;
                float vv1 = acc[i][j][1] + bv;
                float vv2 = acc[i][j][2] + bv;
                float vv3 = acc[i][j][3] + bv;
                if constexpr (EPI == 1){
                    vv0 = gelu_f(vv0); vv1 = gelu_f(vv1);
                    vv2 = gelu_f(vv2); vv3 = gelu_f(vv3);
                }
                unsigned long long self = (unsigned long long)pk_bf16(vv0, vv1)
                                        | ((unsigned long long)pk_bf16(vv2, vv3) << 32);
                unsigned long long nbr = __shfl_xor(self, 1);
                unsigned long long lo = odd ? nbr : self;
                unsigned long long hi = odd ? self : nbr;
                int colb = 16*j + (lf & ~1);
                unsigned int w0 = (unsigned int)((lo >> (16*rsel)) & 0xffffu)
                                | ((unsigned int)((hi >> (16*rsel)) & 0xffffu) << 16);
                unsigned int w1 = (unsigned int)((lo >> (16*(rsel+1))) & 0xffffu)
                                | ((unsigned int)((hi >> (16*(rsel+1))) & 0xffffu) << 16);
                *(unsigned int*)(cs + (16*i + 4*ko + rsel    )*72 + colb) = w0;
                *(unsigned int*)(cs + (16*i + 4*ko + rsel + 1)*72 + colb) = w1;
            }
        }
        const int subrow = lane >> 3, cq = lane & 7;
        #pragma unroll
        for (int rr = 0; rr < 8; ++rr){
            int rl = rr*8 + subrow;
            short8 vv = *(const short8*)(cs + rl*72 + cq*8);
            size_t grow = (size_t)by*128 + mrow + rl;
            int gcol = bx*128 + ncol + cq*8;
            *(short8*)((short*)C + grow*ldc + gcol) = vv;
        }
    }
}

// ---------------------------------------------------------------------------
// merge A: LN1 + prep in one launch. Block ranges: [0,16384) = LN1 rows;
// [16384,19008) = selmap init + 3 weight converts; [19008,19026) = Qhm pad
// zero (rows TOPQ..47, 36864 bf16) so qproj can drop its 2304 no-op blocks.
// ---------------------------------------------------------------------------
__global__ __launch_bounds__(256) void ln1_prep_kernel(const float* __restrict__ x,
                                                       const float* __restrict__ g,
                                                       const float* __restrict__ bt,
                                                       float* __restrict__ xn,
                                                       bf16* __restrict__ xnb,
                                                       const float* __restrict__ in_w,
                                                       const float* __restrict__ w1,
                                                       const float* __restrict__ w2,
                                                       bf16* __restrict__ kvw_b,
                                                       bf16* __restrict__ w1_b,
                                                       bf16* __restrict__ w2_b,
                                                       int* __restrict__ selmap,
                                                       bf16* __restrict__ Qhm)
{
    __shared__ double sbuf[8];
    int bid = blockIdx.x, t = threadIdx.x;
    if (bid >= MROWS){
        int pb = bid - MROWS;
        if (pb < 64){
            selmap[pb*256 + t] = -1;
            return;
        }
        if (pb >= 2624){                      // Qhm pad rows [TOPQ,QPAD)
            int base = (pb - 2624)*2048 + t*8;   // 18 blocks x 2048 elems
            #pragma unroll
            for (int k = 0; k < 8; ++k){
                int idx = base + k;           // idx over (bh, jj, d): bh*576+jj*64+d
                int bh = idx / 576, rem = idx - bh*576;
                Qhm[(size_t)bh*QPAD*DHEAD + (TOPQ + rem/64)*DHEAD + (rem & 63)] =
                    __float2bfloat16(0.f);
            }
            return;
        }
        const float* src; bf16* dst; int i;
        if (pb < 576){       src = in_w + (size_t)DIM*DIM; dst = kvw_b; i = ((pb - 64)*256 + t)*4; }
        else if (pb < 1600){ src = w1;  dst = w1_b; i = ((pb - 576)*256 + t)*4; }
        else {               src = w2;  dst = w2_b; i = ((pb - 1600)*256 + t)*4; }
        float4 v = *(const float4*)(src + i);
        dst[i+0] = __float2bfloat16(v.x);
        dst[i+1] = __float2bfloat16(v.y);
        dst[i+2] = __float2bfloat16(v.z);
        dst[i+3] = __float2bfloat16(v.w);
        return;
    }
    int row = bid;
    size_t base = (size_t)row*DIM;
    double x0 = (double)x[base + t];
    double x1 = (double)x[base + t + 256];
    double a = x0 + x1, q = x0*x0 + x1*x1;
    #pragma unroll
    for (int off = 32; off > 0; off >>= 1){
        a += __shfl_down(a, off);
        q += __shfl_down(q, off);
    }
    if ((t & 63) == 0){ sbuf[t >> 6] = a; sbuf[4 + (t >> 6)] = q; }
    __syncthreads();
    double sx  = sbuf[0] + sbuf[1] + sbuf[2] + sbuf[3];
    double sxx = sbuf[4] + sbuf[5] + sbuf[6] + sbuf[7];
    double m   = sx*(1.0/DIM);
    double var = sxx*(1.0/DIM) - m*m;
    double r = 1.0/sqrt(var + 1e-5);
    double y0 = (x0 - m)*r*(double)g[t]     + (double)bt[t];
    double y1 = (x1 - m)*r*(double)g[t+256] + (double)bt[t+256];
    xn[base+t] = (float)y0;       xn[base+t+256] = (float)y1;
    xnb[base+t] = __float2bfloat16((float)y0);
    xnb[base+t+256] = __float2bfloat16((float)y1);
}

// ---------------------------------------------------------------------------
// merge B: KV projection GEMM (blocks [0,1024)) + xbar column-sum partials
// (blocks [1024,1280), 2 cols/thread).
// ---------------------------------------------------------------------------
__global__ __launch_bounds__(256, 3) void kv_xbar_kernel(const bf16* __restrict__ A,
                                                         const bf16* __restrict__ Bm,
                                                         const float* __restrict__ bias,
                                                         bf16* __restrict__ Khm,
                                                         bf16* __restrict__ Vhm,
                                                         const float* __restrict__ xn,
                                                         double* __restrict__ xbpart)
{
    __shared__ __align__(16) char smem[49152];
    const int t = threadIdx.x;
    if (blockIdx.x >= 1024){
        int cid = blockIdx.x - 1024;          // 0..255
        int b = cid >> 5, c = cid & 31;
        const float* p = xn + ((size_t)b*SEQ + c*64)*DIM + t;
        double s0 = 0.0, s1 = 0.0;
        #pragma unroll 8
        for (int i = 0; i < 64; ++i){
            s0 += (double)p[(size_t)i*DIM];
            s1 += (double)p[(size_t)i*DIM + 256];
        }
        xbpart[((size_t)(b*32 + c))*DIM + t]       = s0;
        xbpart[((size_t)(b*32 + c))*DIM + t + 256] = s1;
        return;
    }
    short* CsBase = (short*)smem;
    const int K = DIM;                        // 512, T = 16
    const int bid = blockIdx.x;
    const int per = 128;                      // 1024 gemm blocks / 8 XCDs
    const int lid = (bid & 7)*per + (bid >> 3);
    const int bx  = lid & 7;                  // lgGX = 3
    const int by  = lid >> 3;

    const int lane = t & 63;
    const int w    = t >> 6;
    const int lf   = lane & 15;
    const int ko   = lane >> 4;
    const int slot = ko ^ ((lf >> 1) & 3);
    const int mrow = (w >> 1)*64, ncol = (w & 1)*64;

    floatx4 acc[4][4];
    floatx4 z = {0.f,0.f,0.f,0.f};
    #pragma unroll
    for (int i = 0; i < 4; ++i)
        #pragma unroll
        for (int j = 0; j < 4; ++j) acc[i][j] = z;

    const int srow = w*16 + (lane >> 2);
    const int sq   = lane & 3;
    const int r0 = srow,      kq0 = sq ^ ((r0 >> 1) & 3);
    const int r1 = 64 + srow, kq1 = sq ^ ((r1 >> 1) & 3);
    const short* ga0 = (const short*)A  + ((size_t)by*128 + r0)*K + kq0*8;
    const short* ga1 = (const short*)A  + ((size_t)by*128 + r1)*K + kq1*8;
    const short* gb0 = (const short*)Bm + ((size_t)bx*128 + r0)*K + kq0*8;
    const short* gb1 = (const short*)Bm + ((size_t)bx*128 + r1)*K + kq1*8;
    char* la0 = smem + w*1024;
    char* la1 = smem + 4096 + w*1024;
    char* lb0 = smem + 8192 + w*1024;
    char* lb1 = smem + 12288 + w*1024;

    auto stage = [&](int off){
        load_lds16(ga0, la0 + off); load_lds16(ga1, la1 + off);
        load_lds16(gb0, lb0 + off); load_lds16(gb1, lb1 + off);
        ga0 += 32; ga1 += 32; gb0 += 32; gb1 += 32;
    };
    auto compute = [&](int off){
        const short* As = (const short*)(smem + off);
        const short* Bs = (const short*)(smem + off + 8192);
        short8 af[4], bfr[4];
        #pragma unroll
        for (int i = 0; i < 4; ++i){
            af[i]  = *(const short8*)(As + (mrow + i*16 + lf)*32 + slot*8);
            bfr[i] = *(const short8*)(Bs + (ncol + i*16 + lf)*32 + slot*8);
        }
        #pragma unroll
        for (int i = 0; i < 4; ++i)
            #pragma unroll
            for (int j = 0; j < 4; ++j)
                acc[i][j] = __builtin_amdgcn_mfma_f32_16x16x32_bf16(af[i], bfr[j], acc[i][j], 0, 0, 0);
    };

    const int T = K >> 5;
    stage(0);
    stage(16384);
    int oc = 0, on = 16384, on2 = 32768;
    for (int kt = 0; kt < T - 2; ++kt){
        asm volatile("s_waitcnt vmcnt(4)" ::: "memory");
        __builtin_amdgcn_s_barrier();
        asm volatile("" ::: "memory");
        stage(on2);
        compute(oc);
        int tmp = oc; oc = on; on = on2; on2 = tmp;
    }
    asm volatile("s_waitcnt vmcnt(4)" ::: "memory");
    __builtin_amdgcn_s_barrier();
    asm volatile("" ::: "memory");
    compute(oc);
    { int tmp = oc; oc = on; on = on2; on2 = tmp; }
    asm volatile("s_waitcnt vmcnt(0)" ::: "memory");
    __builtin_amdgcn_s_barrier();
    asm volatile("" ::: "memory");
    compute(oc);
    __syncthreads();

    // epilogue: bf16 pack -> LDS stage -> coalesced head-major K/V scatter
    short* cs = CsBase + w*(64*72);
    const int odd = lf & 1;
    const int rsel = odd*2;
    #pragma unroll
    for (int j = 0; j < 4; ++j){
        float bv = bias[bx*128 + ncol + j*16 + lf];
        #pragma unroll
        for (int i = 0; i < 4; ++i){
            float vv0 = acc[i][j][0] + bv;
            float vv1 = acc[i][j][1] + bv;
            float vv2 = acc[i][j][2] + bv;
            float vv3 = acc[i][j][3] + bv;
            unsigned long long self = (unsigned long long)pk_bf16(vv0, vv1)
                                    | ((unsigned long long)pk_bf16(vv2, vv3) << 32);
            unsigned long long nbr = __shfl_xor(self, 1);
            unsigned long long lo = odd ? nbr : self;
            unsigned long long hi = odd ? self : nbr;
            int colb = 16*j + (lf & ~1);
            unsigned int w0 = (unsigned int)((lo >> (16*rsel)) & 0xffffu)
                            | ((unsigned int)((hi >> (16*rsel)) & 0xffffu) << 16);
            unsigned int w1 = (unsigned int)((lo >> (16*(rsel+1))) & 0xffffu)
                            | ((unsigned int)((hi >> (16*(rsel+1))) & 0xffffu) << 16);
            *(unsigned int*)(cs + (16*i + 4*ko + rsel    )*72 + colb) = w0;
            *(unsigned int*)(cs + (16*i + 4*ko + rsel + 1)*72 + colb) = w1;
        }
    }
    const int subrow = lane >> 3, cq = lane & 7;
    #pragma unroll
    for (int rr = 0; rr < 8; ++rr){
        int rl = rr*8 + subrow;
        short8 vv = *(const short8*)(cs + rl*72 + cq*8);
        int grow = by*128 + mrow + rl;        // b*SEQ + s
        int b = grow >> 11, s = grow & 2047;
        int gc = bx*128 + ncol + cq*8;
        int h = (gc >> 6) & 7, d = gc & 63;
        bf16* dst = (gc < 512) ? Khm : Vhm;
        *(short8*)((short*)dst + (((size_t)(b*NH + h))*SEQ + s)*DHEAD + d) = vv;
    }
}

__global__ __launch_bounds__(512) void xbar_fin_kernel(const double* __restrict__ part,
                                                       double* __restrict__ xbar_d,
                                                       float* __restrict__ xbar_f){
    int b = blockIdx.x, d = threadIdx.x;
    double s = 0.0;
    for (int c = 0; c < 32; ++c) s += part[((size_t)(b*32 + c))*DIM + d];
    s *= (1.0/SEQ);
    xbar_d[(size_t)b*DIM + d] = s;
    xbar_f[(size_t)b*DIM + d] = (float)s;
}

// sparsity*sqrt(D) = Σxn² - dot(xn_row, xbar); fp64 over the SAME fp32 xn
// values ref uses -> ranking margin >> ref's own fp32 noise.
__global__ __launch_bounds__(256) void sparsity_kernel(const float* __restrict__ xn,
                                                       const double* __restrict__ xbar,
                                                       double* __restrict__ sp)
{
    int row  = blockIdx.x*4 + (threadIdx.x >> 6);
    int lane = threadIdx.x & 63;
    int b    = row >> 11;
    const float* xr = xn + (size_t)row*DIM;
    const double* xb = xbar + (size_t)b*DIM;
    double s = 0.0, d2 = 0.0;
    for (int e = lane; e < DIM; e += 64){
        double xv = (double)xr[e];
        s  += xv*xb[e];
        d2 += xv*xv;
    }
    #pragma unroll
    for (int off = 32; off > 0; off >>= 1){
        s  += __shfl_down(s, off);
        d2 += __shfl_down(d2, off);
    }
    if (lane == 0) sp[row] = d2 - s;
}

// ---------------------------------------------------------------------------
// register-resident top-39: packed monotone u64 order keys. Round-20: wmax
// double-buffered -> ONE __syncthreads per iteration (write buf it&1; next
// iteration writes the other buffer, so no write-after-read race).
// ---------------------------------------------------------------------------
__global__ __launch_bounds__(256) void topk_kernel(const double* __restrict__ sp,
                                                   int* __restrict__ topidx,
                                                   int* __restrict__ selmap,
                                                   float* __restrict__ dout)
{
    __shared__ unsigned long long wmax[2][4];
    int b = blockIdx.x, t = threadIdx.x;
    int lane = t & 63, w = t >> 6;

    unsigned long long pk[8];
    #pragma unroll
    for (int i = 0; i < 8; ++i){
        int idx = i*256 + t;                          // coalesced
        unsigned long long bits =
            (unsigned long long)__double_as_longlong(sp[(size_t)b*SEQ + idx]);
        unsigned long long m = (bits & 0x8000000000000000ull)
                             ? ~bits : (bits | 0x8000000000000000ull);
        pk[i] = (m & ~2047ull) | (unsigned long long)(2047 - idx);
    }
    unsigned long long lm = pk[0];
    #pragma unroll
    for (int i = 1; i < 8; ++i) lm = (pk[i] > lm) ? pk[i] : lm;

    for (int it = 0; it < TOPQ; ++it){
        int pbuf = it & 1;
        unsigned long long m = lm;
        #pragma unroll
        for (int off = 32; off > 0; off >>= 1){
            unsigned long long o = __shfl_xor(m, off);
            m = (o > m) ? o : m;
        }
        if (lane == 0) wmax[pbuf][w] = m;
        __syncthreads();
        unsigned long long g01 = (wmax[pbuf][0] > wmax[pbuf][1]) ? wmax[pbuf][0] : wmax[pbuf][1];
        unsigned long long g23 = (wmax[pbuf][2] > wmax[pbuf][3]) ? wmax[pbuf][2] : wmax[pbuf][3];
        unsigned long long g = (g01 > g23) ? g01 : g23;
        int idx = 2047 - (int)(g & 2047ull);
        if (t == 0){
            topidx[b*64 + it] = idx;
            selmap[(size_t)b*SEQ + idx] = it;
        }
        if ((idx & 255) == t){                        // owner removes + recompute
            int slot = idx >> 8;
            #pragma unroll
            for (int i = 0; i < 8; ++i) if (i == slot) pk[i] = 0;
            lm = pk[0];
            #pragma unroll
            for (int i = 1; i < 8; ++i) lm = (pk[i] > lm) ? pk[i] : lm;
        }
    }
    if (b == 0 && t == 0) dout[(size_t)MROWS*DIM] = (float)TOPQ/(float)SEQ;
}

// ---------------------------------------------------------------------------
// qproj v2: 32x-parallel. grid (32, TOPQ, BATCH) — pad rows pre-zeroed in
// ln1_prep, so the 2304 former no-op blocks are gone.
// ---------------------------------------------------------------------------
__global__ __launch_bounds__(256) void qproj_kernel(const float* __restrict__ xn,
                                                    const float* __restrict__ in_w,
                                                    const float* __restrict__ in_b,
                                                    const int* __restrict__ topidx,
                                                    bf16* __restrict__ Qhm)
{
    __shared__ float qr[DIM];
    int dblk = blockIdx.x, j = blockIdx.y, b = blockIdx.z;
    int t = threadIdx.x;
    int o = t >> 4, ks = t & 15;
    int d0 = dblk*16 + o;
    int h = d0 >> 6, d = d0 & 63;
    int srow = topidx[b*64 + j];
    const float* xr = xn + ((size_t)(b*SEQ + srow))*DIM;
    qr[t] = xr[t]; qr[t + 256] = xr[t + 256];
    __syncthreads();
    const float* wr = in_w + (size_t)d0*DIM;
    float s = 0.f;
    #pragma unroll
    for (int i = 0; i < 8; ++i){
        int e = i*64 + ks*4;
        float4 wv = *(const float4*)(wr + e);
        float4 cv = *(const float4*)(qr + e);
        s += cv.x*wv.x + cv.y*wv.y + cv.z*wv.z + cv.w*wv.w;
    }
    #pragma unroll
    for (int off = 8; off > 0; off >>= 1) s += __shfl_down(s, off, 16);
    if (ks == 0)
        Qhm[((size_t)(b*NH + h)*QPAD + j)*DHEAD + d] = __float2bfloat16(s + in_b[d0]);
}

// ---------------------------------------------------------------------------
// MFMA split-K attention partial (KC=64, 2 blocks/CU).
// ---------------------------------------------------------------------------
__global__ __launch_bounds__(256, 1) void attn_mfma_kernel(const bf16* __restrict__ Qhm,
                                                           const bf16* __restrict__ Khm,
                                                           const bf16* __restrict__ Vhm,
                                                           float* __restrict__ part)
{
    __shared__ __align__(16) short vsm[4*4096];   // 32 KB: 4 waves x (64k x 64d)
    const int bh   = blockIdx.z*NH + blockIdx.y;
    const int w    = threadIdx.x >> 6;
    const int lane = threadIdx.x & 63;
    const int ch   = blockIdx.x*4 + w;           // chunk 0..31
    const int kb   = ch*KC;                      // first key of chunk
    const int lf   = lane & 15;
    const int g    = lane >> 4;

    short* vbase = vsm + w*4096;
    const short* vg = (const short*)Vhm + ((size_t)bh*SEQ + kb)*DHEAD;
    {
        const int kh = lane >> 1, dh = (lane & 1)*8;
        #pragma unroll
        for (int L = 0; L < 8; ++L){
            int k = (L & 1)*32 + kh;
            int d = (L >> 1)*16 + dh;
            load_lds16(vg + (size_t)k*DHEAD + d, vbase + L*512);
        }
    }

    short8 qf[3][2];
    const short* qp = (const short*)Qhm + (size_t)bh*QPAD*DHEAD;
    #pragma unroll
    for (int nt = 0; nt < 3; ++nt)
        #pragma unroll
        for (int s = 0; s < 2; ++s)
            qf[nt][s] = *(const short8*)(qp + (nt*16 + lf)*DHEAD + s*32 + g*8);

    floatx4 sa[4][3];
    floatx4 z = {0.f,0.f,0.f,0.f};
    #pragma unroll
    for (int mt = 0; mt < 4; ++mt)
        #pragma unroll
        for (int nt = 0; nt < 3; ++nt) sa[mt][nt] = z;

    const short* kp = (const short*)Khm + ((size_t)bh*SEQ + kb)*DHEAD;
    #pragma unroll
    for (int mt = 0; mt < 4; ++mt){
        const short* kr = kp + (size_t)(mt*16 + lf)*DHEAD + g*8;
        short8 kf0 = *(const short8*)(kr);
        short8 kf1 = *(const short8*)(kr + 32);
        #pragma unroll
        for (int nt = 0; nt < 3; ++nt){
            sa[mt][nt] = __builtin_amdgcn_mfma_f32_16x16x32_bf16(kf0, qf[nt][0], sa[mt][nt], 0, 0, 0);
            sa[mt][nt] = __builtin_amdgcn_mfma_f32_16x16x32_bf16(kf1, qf[nt][1], sa[mt][nt], 0, 0, 0);
        }
    }

    float mx[3], ls[3];
    #pragma unroll
    for (int nt = 0; nt < 3; ++nt){
        float m = sa[0][nt][0];
        #pragma unroll
        for (int mt = 0; mt < 4; ++mt)
            #pragma unroll
            for (int r = 0; r < 4; ++r) m = fmaxf(m, sa[mt][nt][r]);
        m = fmaxf(m, __shfl_xor(m, 16));
        m = fmaxf(m, __shfl_xor(m, 32));
        float l = 0.f;
        #pragma unroll
        for (int mt = 0; mt < 4; ++mt){
            #pragma unroll
            for (int r = 0; r < 4; ++r){
                float p = __expf((sa[mt][nt][r] - m)*0.125f);   // 1/sqrt(64)
                sa[mt][nt][r] = p;
                l += p;
            }
        }
        l += __shfl_xor(l, 16);
        l += __shfl_xor(l, 32);
        mx[nt] = m; ls[nt] = l;
    }

    asm volatile("s_waitcnt vmcnt(0)" ::: "memory");   // V staging landed
    floatx4 oacc[3][4];
    #pragma unroll
    for (int mi = 0; mi < 3; ++mi)
        #pragma unroll
        for (int dt = 0; dt < 4; ++dt) oacc[mi][dt] = z;

    #pragma unroll
    for (int t = 0; t < 4; ++t){
        sh4 pa[3];
        #pragma unroll
        for (int mi = 0; mi < 3; ++mi){
            union { sh4 v; unsigned u[2]; } pk;
            pk.u[0] = pk_bf16(sa[t][mi][0], sa[t][mi][1]);
            pk.u[1] = pk_bf16(sa[t][mi][2], sa[t][mi][3]);
            pa[mi] = pk.v;
        }
        #pragma unroll
        for (int dt = 0; dt < 4; ++dt){
            sh4 vf = tr16_read(vbase + dt*1024 + (t*16 + 4*g)*16 + lf);
            #pragma unroll
            for (int mi = 0; mi < 3; ++mi)
                oacc[mi][dt] = mfma16(pa[mi], vf, oacc[mi][dt]);
        }
    }

    float* pbase = part + ((size_t)bh*TOPQ*NKC + ch)*PSTR;
    #pragma unroll
    for (int mi = 0; mi < 3; ++mi){
        #pragma unroll
        for (int r = 0; r < 4; ++r){
            int q = mi*16 + 4*g + r;
            if (q < TOPQ){
                float* pp = pbase + (size_t)q*NKC*PSTR;
                #pragma unroll
                for (int dt = 0; dt < 4; ++dt)
                    pp[dt*16 + lf] = oacc[mi][dt][r];
            }
        }
    }
    #pragma unroll
    for (int nt = 0; nt < 3; ++nt){
        int q = nt*16 + lf;
        if (g == 3 && q < TOPQ){
            float* pp = pbase + (size_t)q*NKC*PSTR;
            pp[64] = mx[nt]*0.125f;
            pp[65] = ls[nt];
        }
    }
}

// pass 2: merge 32 partials per (b,h,q); wave per (q,h), 4 q per block -> ctxb.
__global__ __launch_bounds__(256) void attn_reduce_kernel(const float* __restrict__ part,
                                                          float* __restrict__ ctx)
{
    int qc = blockIdx.x, h = blockIdx.y, b = blockIdx.z;
    int w = threadIdx.x >> 6, lane = threadIdx.x & 63;
    int q = qc*4 + w;
    if (q >= TOPQ) return;
    const float* pb = part + (((size_t)(b*NH + h))*TOPQ + q)*NKC*PSTR;
    float M = -3.402823466e38f;
    #pragma unroll
    for (int i = 0; i < NKC; ++i) M = fmaxf(M, pb[i*PSTR + 64]);
    float L = 0.f, a = 0.f;
    #pragma unroll
    for (int i = 0; i < NKC; ++i){
        float sc = __expf(pb[i*PSTR + 64] - M);
        L += pb[i*PSTR + 65]*sc;
        a += pb[i*PSTR + lane]*sc;
    }
    ctx[((size_t)(b*TOPQ + q))*DIM + h*DHEAD + lane] = a/L;
}

// ---------------------------------------------------------------------------
// outproj v2: 32x-parallel (proven round-16).
// ---------------------------------------------------------------------------
__global__ __launch_bounds__(256) void outproj_kernel(const float* __restrict__ ctx,
                                                      const float* __restrict__ ow,
                                                      const float* __restrict__ ob,
                                                      float* __restrict__ sout)
{
    __shared__ float cr[DIM];
    int dblk = blockIdx.x, q = blockIdx.y, b = blockIdx.z;
    int t = threadIdx.x;
    const float* xr = ctx + ((size_t)(b*TOPQ + q))*DIM;
    cr[t] = xr[t]; cr[t + 256] = xr[t + 256];
    __syncthreads();
    int o = t >> 4, ks = t & 15;
    int d0 = dblk*16 + o;
    const float* wr = ow + (size_t)d0*DIM;
    float s = 0.f;
    #pragma unroll
    for (int i = 0; i < 8; ++i){
        int e = i*64 + ks*4;
        float4 wv = *(const float4*)(wr + e);
        float4 cv = *(const float4*)(cr + e);
        s += cv.x*wv.x + cv.y*wv.y + cv.z*wv.z + cv.w*wv.w;
    }
    #pragma unroll
    for (int off = 8; off > 0; off >>= 1) s += __shfl_down(s, off, 16);
    if (ks == 0) sout[((size_t)(b*TOPQ + q))*DIM + d0] = s + ob[d0];
}

// ---------------------------------------------------------------------------
// res+LN2: ONE-PASS paired fp32 reduction (Σv, Σv²); 1 barrier.
// ---------------------------------------------------------------------------
__global__ __launch_bounds__(256) void res_ln2_kernel(const float* __restrict__ x,
                                                      const float* __restrict__ xbar,
                                                      const float* __restrict__ sout,
                                                      const int* __restrict__ selmap,
                                                      const float* __restrict__ g2,
                                                      const float* __restrict__ bt2,
                                                      float* __restrict__ x2,
                                                      bf16* __restrict__ hb)
{
    __shared__ float sbuf[8];
    int row = blockIdx.x;
    int b = row >> 11;
    int t = threadIdx.x;
    int slot = selmap[row];
    const float* ar = (slot >= 0) ? (sout + ((size_t)(b*TOPQ + slot))*DIM)
                                  : (xbar + (size_t)b*DIM);
    size_t base = (size_t)row*DIM;
    float v0 = x[base + t]       + ar[t];
    float v1 = x[base + t + 256] + ar[t + 256];
    x2[base + t] = v0; x2[base + t + 256] = v1;
    float a = v0 + v1, q = v0*v0 + v1*v1;
    #pragma unroll
    for (int off = 32; off > 0; off >>= 1){
        a += __shfl_down(a, off);
        q += __shfl_down(q, off);
    }
    if ((t & 63) == 0){ sbuf[t >> 6] = a; sbuf[4 + (t >> 6)] = q; }
    __syncthreads();
    float sv  = sbuf[0] + sbuf[1] + sbuf[2] + sbuf[3];
    float svv = sbuf[4] + sbuf[5] + sbuf[6] + sbuf[7];
    float m   = sv*(1.f/DIM);
    float var = svv*(1.f/DIM) - m*m;
    float r = 1.f/sqrtf(var + 1e-5f);
    hb[base + t]       = __float2bfloat16((v0 - m)*r*g2[t]     + bt2[t]);
    hb[base + t + 256] = __float2bfloat16((v1 - m)*r*g2[t+256] + bt2[t+256]);
}

// ---------------------------------------------------------------------------
extern "C" void kernel_launch(void* const* d_in, const int* in_sizes, int n_in,
                              void* d_out, int out_size, void* d_ws, size_t ws_size,
                              hipStream_t stream)
{
    (void)in_sizes; (void)n_in; (void)out_size; (void)ws_size;
    const float* x     = (const float*)d_in[0];
    const float* ln1_g = (const float*)d_in[1];
    const float* ln1_b = (const float*)d_in[2];
    const float* in_w  = (const float*)d_in[3];
    const float* in_b  = (const float*)d_in[4];
    const float* out_w = (const float*)d_in[5];
    const float* out_b = (const float*)d_in[6];
    const float* ln2_g = (const float*)d_in[7];
    const float* ln2_b = (const float*)d_in[8];
    const float* w1    = (const float*)d_in[9];
    const float* b1    = (const float*)d_in[10];
    const float* w2    = (const float*)d_in[11];
    const float* b2    = (const float*)d_in[12];
    float* out = (float*)d_out;

    const size_t MB = 1024*1024;
    char* base = (char*)d_ws;
    float* xn_f  = (float*)base;                 // [0,32MiB); reused as x2_f later
    bf16*  xn_b  = (bf16*)(base + 32*MB);        // dead after kv-gemm -> h_b
    bf16*  Khm   = (bf16*)(base + 48*MB);
    bf16*  Vhm   = (bf16*)(base + 64*MB);
    bf16*  h_b   = (bf16*)(base + 32*MB);
    bf16*  h1_b  = (bf16*)(base + 48*MB);        // overwrites Khm/Vhm after attn
    float* x2_f  = xn_f;
    // apart (21 MiB) lives at [80,101) MiB: free during attention (h1_b rows
    // covering it are written only by FFN1, after attn_reduce consumed apart).
    float* apart = (float*)(base + 80*MB);
    char* p = base + 112*MB;
    bf16*  kvw_b  = (bf16*)p;  p += (size_t)1024*DIM*2;        // in_w rows [512,1536) bf16
    bf16*  w1_b   = (bf16*)p;  p += (size_t)FFD*DIM*2;
    bf16*  w2_b   = (bf16*)p;  p += (size_t)DIM*FFD*2;
    double* xbpart= (double*)p; p += (size_t)BATCH*32*DIM*8;
    double* xbar_d= (double*)p; p += (size_t)BATCH*DIM*8;
    float* xbar_f = (float*)p;  p += (size_t)BATCH*DIM*4;
    double* spars = (double*)p; p += (size_t)MROWS*8;
    int*   topidx = (int*)p;    p += (size_t)BATCH*64*4;
    int*   selmap = (int*)p;    p += (size_t)MROWS*4;
    bf16*  Qhm    = (bf16*)p;   p += (size_t)BATCH*NH*QPAD*DHEAD*2;   // 384 KiB
    float* ctxb   = (float*)p;  p += (size_t)BATCH*TOPQ*DIM*4;
    float* sout   = (float*)p;  p += (size_t)BATCH*TOPQ*DIM*4;

    // 12 dispatches; topk 1-sync/iter; qproj pad blocks removed (pre-zeroed).
    ln1_prep_kernel<<<MROWS + 2624 + 18, 256, 0, stream>>>(
        x, ln1_g, ln1_b, xn_f, xn_b, in_w, w1, w2, kvw_b, w1_b, w2_b, selmap, Qhm);
    kv_xbar_kernel<<<1280, 256, 0, stream>>>(
        xn_b, kvw_b, in_b + DIM, Khm, Vhm, xn_f, xbpart);
    xbar_fin_kernel<<<BATCH, 512, 0, stream>>>(xbpart, xbar_d, xbar_f);
    sparsity_kernel<<<MROWS/4, 256, 0, stream>>>(xn_f, xbar_d, spars);
    topk_kernel<<<BATCH, 256, 0, stream>>>(spars, topidx, selmap, out);
    qproj_kernel<<<dim3(32, TOPQ, BATCH), 256, 0, stream>>>(xn_f, in_w, in_b, topidx, Qhm);
    attn_mfma_kernel<<<dim3(NKC/4, NH, BATCH), 256, 0, stream>>>(Qhm, Khm, Vhm, apart);
    attn_reduce_kernel<<<dim3((TOPQ + 3)/4, NH, BATCH), 256, 0, stream>>>(apart, ctxb);
    outproj_kernel<<<dim3(32, TOPQ, BATCH), 256, 0, stream>>>(ctxb, out_w, out_b, sout);
    res_ln2_kernel<<<MROWS, 256, 0, stream>>>(x, xbar_f, sout, selmap, ln2_g, ln2_b, x2_f, h_b);
    // FFN1: grid 16x128 -> 2048 blocks, lgGX=4
    gemm128_kernel<1, bf16><<<2048, 256, 0, stream>>>(
        h_b, w1_b, b1, h1_b, nullptr, nullptr, DIM, FFD, 4);
    // FFN2: grid 4x128 -> 512 blocks, lgGX=2
    gemm128_kernel<2, float><<<512, 256, 0, stream>>>(
        h1_b, w2_b, b2, out, x2_f, nullptr, FFD, DIM, 2);
}